// Round 1
// baseline (7887.954 us; speedup 1.0000x reference)
//
#include <hip/hip_runtime.h>

#define NB     16384
#define TEAM   5
#define NPAIR  20
#define PD     256
#define HD     256
#define H1D    512
#define NPLAY  (NB*TEAM)      // 81920
#define NROWS  (NB*NPAIR)     // 327680

__device__ __forceinline__ float silu_f(float x){ return x / (1.0f + __expf(-x)); }

// ---------------------------------------------------------------------------
// Kernel A: per 16 players: x = emb[tid]; h1 = silu(W1 x + b1); h = W2 h1 + b2
// LDS: Xs 16x260 (16.6K) + H1s 16x516 (33K) + Ws 256x20 (20.5K) = 70.1K -> 2 blk/CU
// ---------------------------------------------------------------------------
__global__ __launch_bounds__(256,2) void k_fm(
    const int* __restrict__ tids, const float* __restrict__ emb,
    const float* __restrict__ w1, const float* __restrict__ b1,
    const float* __restrict__ w2, const float* __restrict__ b2,
    float* __restrict__ Hout)
{
  __shared__ float Xs[16*260];
  __shared__ float H1s[16*516];
  __shared__ float Ws[256*20];
  const int t   = threadIdx.x;
  const int m0  = blockIdx.x * 16;

  // ---- load X: 16 gathered emb rows, coalesced (16 lanes x float4 per row)
  {
    const int i = t >> 4, l = t & 15;
    const int tid = tids[m0 + i];
    const float* src = emb + (size_t)tid * PD;
    float* dst = Xs + i * 260;
    #pragma unroll
    for (int q = 0; q < 4; ++q) {
      const int c = q * 64 + l * 4;
      *reinterpret_cast<float4*>(dst + c) = *reinterpret_cast<const float4*>(src + c);
    }
  }

  const int rowg = t & 7;    // 0..7  (rows rowg, rowg+8)
  const int colg = t >> 3;   // 0..31 (cols colg + 32j)

  // ---- phase 1: H1 = silu(X @ W1^T + b1), 512 cols in two halves of 256
  for (int half = 0; half < 2; ++half) {
    float acc[2][8];
    #pragma unroll
    for (int i = 0; i < 2; ++i)
      #pragma unroll
      for (int j = 0; j < 8; ++j) acc[i][j] = 0.0f;

    for (int kt = 0; kt < PD; kt += 16) {
      __syncthreads();
      { // stage W1 tile: 256 out-cols x 16 k
        const int n = t >> 2, k4 = (t & 3) * 4;
        #pragma unroll
        for (int pp = 0; pp < 4; ++pp) {
          const int nn = pp * 64 + n;
          *reinterpret_cast<float4*>(Ws + nn * 20 + k4) =
            *reinterpret_cast<const float4*>(w1 + (size_t)(half * 256 + nn) * PD + kt + k4);
        }
      }
      __syncthreads();
      #pragma unroll
      for (int k = 0; k < 16; k += 4) {
        float4 xa[2], wb[8];
        #pragma unroll
        for (int i = 0; i < 2; ++i)
          xa[i] = *reinterpret_cast<const float4*>(Xs + (rowg + 8*i) * 260 + kt + k);
        #pragma unroll
        for (int j = 0; j < 8; ++j)
          wb[j] = *reinterpret_cast<const float4*>(Ws + (colg + 32*j) * 20 + k);
        #pragma unroll
        for (int i = 0; i < 2; ++i)
          #pragma unroll
          for (int j = 0; j < 8; ++j) {
            acc[i][j] = fmaf(xa[i].x, wb[j].x, acc[i][j]);
            acc[i][j] = fmaf(xa[i].y, wb[j].y, acc[i][j]);
            acc[i][j] = fmaf(xa[i].z, wb[j].z, acc[i][j]);
            acc[i][j] = fmaf(xa[i].w, wb[j].w, acc[i][j]);
          }
      }
    }
    // bias + silu -> H1s
    #pragma unroll
    for (int i = 0; i < 2; ++i) {
      const int r = rowg + 8*i;
      #pragma unroll
      for (int j = 0; j < 8; ++j) {
        const int c = colg + 32*j;
        const float v = acc[i][j] + b1[half * 256 + c];
        H1s[r * 516 + half * 256 + c] = silu_f(v);
      }
    }
  }

  // ---- phase 2: H2 = H1 @ W2^T + b2   (K = 512)
  float acc2[2][8];
  #pragma unroll
  for (int i = 0; i < 2; ++i)
    #pragma unroll
    for (int j = 0; j < 8; ++j) acc2[i][j] = 0.0f;

  for (int kt = 0; kt < H1D; kt += 16) {
    __syncthreads();
    { // stage W2 tile: 256 out-cols x 16 k
      const int n = t >> 2, k4 = (t & 3) * 4;
      #pragma unroll
      for (int pp = 0; pp < 4; ++pp) {
        const int nn = pp * 64 + n;
        *reinterpret_cast<float4*>(Ws + nn * 20 + k4) =
          *reinterpret_cast<const float4*>(w2 + (size_t)nn * H1D + kt + k4);
      }
    }
    __syncthreads();
    #pragma unroll
    for (int k = 0; k < 16; k += 4) {
      float4 xa[2], wb[8];
      #pragma unroll
      for (int i = 0; i < 2; ++i)
        xa[i] = *reinterpret_cast<const float4*>(H1s + (rowg + 8*i) * 516 + kt + k);
      #pragma unroll
      for (int j = 0; j < 8; ++j)
        wb[j] = *reinterpret_cast<const float4*>(Ws + (colg + 32*j) * 20 + k);
      #pragma unroll
      for (int i = 0; i < 2; ++i)
        #pragma unroll
        for (int j = 0; j < 8; ++j) {
          acc2[i][j] = fmaf(xa[i].x, wb[j].x, acc2[i][j]);
          acc2[i][j] = fmaf(xa[i].y, wb[j].y, acc2[i][j]);
          acc2[i][j] = fmaf(xa[i].z, wb[j].z, acc2[i][j]);
          acc2[i][j] = fmaf(xa[i].w, wb[j].w, acc2[i][j]);
        }
    }
  }
  __syncthreads();
  // epilogue: +b2, stage into Xs (dead), then coalesced store
  #pragma unroll
  for (int i = 0; i < 2; ++i) {
    const int r = rowg + 8*i;
    #pragma unroll
    for (int j = 0; j < 8; ++j) {
      const int c = colg + 32*j;
      Xs[r * 260 + c] = acc2[i][j] + b2[c];
    }
  }
  __syncthreads();
  #pragma unroll
  for (int q = 0; q < 4; ++q) {
    const int row = q * 4 + (t >> 6);
    const int c4  = (t & 63) * 4;
    *reinterpret_cast<float4*>(Hout + (size_t)(m0 + row) * PD + c4) =
      *reinterpret_cast<const float4*>(Xs + row * 260 + c4);
  }
}

// ---------------------------------------------------------------------------
// Kernel B: per 4 batches (20 players): WA = H @ att_w^T + att_b (kept in LDS),
// then score[b,i,j] = dot(WA[i], H[j]) for the 20 ordered pairs.
// LDS: Hl 20x260 + WAs 20x260 + Ws 256x20 = 62K -> 2 blk/CU
// ---------------------------------------------------------------------------
__global__ __launch_bounds__(256,2) void k_att_score(
    const float* __restrict__ Hin, const float* __restrict__ attw,
    const float* __restrict__ attb, float* __restrict__ SC)
{
  __shared__ float Hl[20*260];
  __shared__ float WAs[20*260];
  __shared__ float Ws[256*20];
  const int t  = threadIdx.x;
  const int b0 = blockIdx.x * 4;

  { // load 20 contiguous player rows
    const float* src = Hin + (size_t)b0 * TEAM * PD;
    const int i = t >> 4, l = t & 15;
    #pragma unroll
    for (int q = 0; q < 4; ++q) {
      const int c = q * 64 + l * 4;
      *reinterpret_cast<float4*>(Hl + i * 260 + c) =
        *reinterpret_cast<const float4*>(src + (size_t)i * PD + c);
    }
    if (t < 64) {
      const int i2 = 16 + (t >> 4), l2 = t & 15;
      #pragma unroll
      for (int q = 0; q < 4; ++q) {
        const int c = q * 64 + l2 * 4;
        *reinterpret_cast<float4*>(Hl + i2 * 260 + c) =
          *reinterpret_cast<const float4*>(src + (size_t)i2 * PD + c);
      }
    }
  }

  const int rowg = t & 3;   // rows rowg + 4i (i=0..4)
  const int colg = t >> 2;  // cols colg + 64j (j=0..3)
  float acc[5][4];
  #pragma unroll
  for (int i = 0; i < 5; ++i)
    #pragma unroll
    for (int j = 0; j < 4; ++j) acc[i][j] = 0.0f;

  for (int kt = 0; kt < HD; kt += 16) {
    __syncthreads();
    { // stage att_w tile
      const int n = t >> 2, k4 = (t & 3) * 4;
      #pragma unroll
      for (int pp = 0; pp < 4; ++pp) {
        const int nn = pp * 64 + n;
        *reinterpret_cast<float4*>(Ws + nn * 20 + k4) =
          *reinterpret_cast<const float4*>(attw + (size_t)nn * HD + kt + k4);
      }
    }
    __syncthreads();
    #pragma unroll
    for (int k = 0; k < 16; k += 4) {
      float4 xa[5], wb[4];
      #pragma unroll
      for (int i = 0; i < 5; ++i)
        xa[i] = *reinterpret_cast<const float4*>(Hl + (rowg + 4*i) * 260 + kt + k);
      #pragma unroll
      for (int j = 0; j < 4; ++j)
        wb[j] = *reinterpret_cast<const float4*>(Ws + (colg + 64*j) * 20 + k);
      #pragma unroll
      for (int i = 0; i < 5; ++i)
        #pragma unroll
        for (int j = 0; j < 4; ++j) {
          acc[i][j] = fmaf(xa[i].x, wb[j].x, acc[i][j]);
          acc[i][j] = fmaf(xa[i].y, wb[j].y, acc[i][j]);
          acc[i][j] = fmaf(xa[i].z, wb[j].z, acc[i][j]);
          acc[i][j] = fmaf(xa[i].w, wb[j].w, acc[i][j]);
        }
    }
  }
  // +att_b -> WAs
  #pragma unroll
  for (int i = 0; i < 5; ++i) {
    const int r = rowg + 4*i;
    #pragma unroll
    for (int j = 0; j < 4; ++j) {
      const int c = colg + 64*j;
      WAs[r * 260 + c] = acc[i][j] + attb[c];
    }
  }
  __syncthreads();

  // score phase: wave w handles batch b0+w; 64 lanes x 4 elems per dot
  {
    const int w = t >> 6, l = t & 63;
    #pragma unroll
    for (int p = 0; p < NPAIR; ++p) {
      const int i1 = p >> 2, jj = p & 3;
      const int i2 = jj + (jj >= i1 ? 1 : 0);
      const float4 a4 = *reinterpret_cast<const float4*>(WAs + (w*TEAM + i1) * 260 + l * 4);
      const float4 b4 = *reinterpret_cast<const float4*>(Hl  + (w*TEAM + i2) * 260 + l * 4);
      float v = a4.x*b4.x + a4.y*b4.y + a4.z*b4.z + a4.w*b4.w;
      #pragma unroll
      for (int off = 32; off > 0; off >>= 1) v += __shfl_xor(v, off);
      if (l == 0) SC[(size_t)(b0 + w) * NPAIR + p] = v;
    }
  }
}

// ---------------------------------------------------------------------------
// Kernel C: pair MLP. Block = 8 batches (160 pair rows) x 64 of 512 cols.
// prod rows formed on the fly from 40 staged h rows; mlp2 dot fused in epilogue.
// LDS: Hl 40x260 (41.6K) + Ws 64x20 + red 160x8 + Wb/Ww = 52.3K -> 3 blk/CU
// ---------------------------------------------------------------------------
__global__ __launch_bounds__(256,3) void k_mlp(
    const float* __restrict__ Hin, const float* __restrict__ w1,
    const float* __restrict__ b1, const float* __restrict__ w2,
    float* __restrict__ PART)
{
  __shared__ float Hl[40*260];
  __shared__ float Ws[64*20];
  __shared__ float red[160*8];
  __shared__ float Wb[64];
  __shared__ float Ww[64];
  const int t    = threadIdx.x;
  const int blkx = blockIdx.x;
  const int cy   = blockIdx.y;
  const int b0   = blkx * 8;

  { // load 40 contiguous player rows
    const float* src = Hin + (size_t)b0 * TEAM * PD;
    const int i = t >> 4, l = t & 15;
    #pragma unroll
    for (int q = 0; q < 4; ++q) {
      const int c = q * 64 + l * 4;
      *reinterpret_cast<float4*>(Hl + i * 260 + c) =
        *reinterpret_cast<const float4*>(src + (size_t)i * PD + c);
      *reinterpret_cast<float4*>(Hl + (i+16) * 260 + c) =
        *reinterpret_cast<const float4*>(src + (size_t)(i+16) * PD + c);
    }
    if (t < 128) {
      const int i2 = 32 + (t >> 4), l2 = t & 15;
      #pragma unroll
      for (int q = 0; q < 4; ++q) {
        const int c = q * 64 + l2 * 4;
        *reinterpret_cast<float4*>(Hl + i2 * 260 + c) =
          *reinterpret_cast<const float4*>(src + (size_t)i2 * PD + c);
      }
    }
    if (t < 64) { Wb[t] = b1[cy * 64 + t]; Ww[t] = w2[cy * 64 + t]; }
  }

  const int rowg = t & 31;  // rows rowg + 32i (i=0..4)
  const int colg = t >> 5;  // cols colg + 8j (j=0..7)

  int oa[5], ob[5];
  #pragma unroll
  for (int i = 0; i < 5; ++i) {
    const int r = rowg + 32*i;
    const int q = r / NPAIR;
    const int p = r - q * NPAIR;
    const int i1 = p >> 2, jj = p & 3;
    const int i2 = jj + (jj >= i1 ? 1 : 0);
    oa[i] = (q * TEAM + i1) * 260;
    ob[i] = (q * TEAM + i2) * 260;
  }

  float acc[5][8];
  #pragma unroll
  for (int i = 0; i < 5; ++i)
    #pragma unroll
    for (int j = 0; j < 8; ++j) acc[i][j] = 0.0f;

  for (int kt = 0; kt < PD; kt += 16) {
    __syncthreads();
    { // stage mlp_w1 tile: 64 cols x 16 k
      const int n = t >> 2, k4 = (t & 3) * 4;
      *reinterpret_cast<float4*>(Ws + n * 20 + k4) =
        *reinterpret_cast<const float4*>(w1 + (size_t)(cy * 64 + n) * PD + kt + k4);
    }
    __syncthreads();
    #pragma unroll
    for (int k = 0; k < 16; k += 4) {
      float4 pr[5], wb[8];
      #pragma unroll
      for (int i = 0; i < 5; ++i) {
        const float4 a4 = *reinterpret_cast<const float4*>(Hl + oa[i] + kt + k);
        const float4 b4 = *reinterpret_cast<const float4*>(Hl + ob[i] + kt + k);
        pr[i].x = a4.x * b4.x; pr[i].y = a4.y * b4.y;
        pr[i].z = a4.z * b4.z; pr[i].w = a4.w * b4.w;
      }
      #pragma unroll
      for (int j = 0; j < 8; ++j)
        wb[j] = *reinterpret_cast<const float4*>(Ws + (colg + 8*j) * 20 + k);
      #pragma unroll
      for (int i = 0; i < 5; ++i)
        #pragma unroll
        for (int j = 0; j < 8; ++j) {
          acc[i][j] = fmaf(pr[i].x, wb[j].x, acc[i][j]);
          acc[i][j] = fmaf(pr[i].y, wb[j].y, acc[i][j]);
          acc[i][j] = fmaf(pr[i].z, wb[j].z, acc[i][j]);
          acc[i][j] = fmaf(pr[i].w, wb[j].w, acc[i][j]);
        }
    }
  }

  // epilogue: silu + mlp2-dot partial over this block's 64 cols
  #pragma unroll
  for (int i = 0; i < 5; ++i) {
    const int r = rowg + 32*i;
    float s = 0.0f;
    #pragma unroll
    for (int j = 0; j < 8; ++j) {
      const int c = colg + 8*j;
      s += silu_f(acc[i][j] + Wb[c]) * Ww[c];
    }
    red[r * 8 + colg] = s;
  }
  __syncthreads();
  if (t < 160) {
    float s = 0.0f;
    #pragma unroll
    for (int g = 0; g < 8; ++g) s += red[t * 8 + g];
    PART[(size_t)cy * NROWS + (size_t)blkx * 160 + t] = s;
  }
}

// ---------------------------------------------------------------------------
// Kernel D: one thread per batch: order2 = sum(PART)+mlp_b2; softmax(score)
// over each anchor's 4 partners; out[b] = sum order2*normal.
// ---------------------------------------------------------------------------
__global__ void k_final(const float* __restrict__ SC, const float* __restrict__ PART,
                        const float* __restrict__ mb2, float* __restrict__ out)
{
  const int b = blockIdx.x * 256 + threadIdx.x;
  if (b >= NB) return;
  const float bias2 = mb2[0];
  float ord[NPAIR], sc[NPAIR];
  #pragma unroll
  for (int p = 0; p < NPAIR; ++p) {
    float s = bias2;
    #pragma unroll
    for (int g = 0; g < 8; ++g) s += PART[(size_t)g * NROWS + (size_t)b * NPAIR + p];
    ord[p] = s;
    sc[p] = SC[(size_t)b * NPAIR + p];
  }
  float res = 0.0f;
  #pragma unroll
  for (int i = 0; i < TEAM; ++i) {
    float m = sc[4*i];
    #pragma unroll
    for (int jj = 1; jj < 4; ++jj) m = fmaxf(m, sc[4*i + jj]);
    float e[4], d = 0.0f;
    #pragma unroll
    for (int jj = 0; jj < 4; ++jj) { e[jj] = __expf(sc[4*i + jj] - m); d += e[jj]; }
    const float inv = 1.0f / d;
    #pragma unroll
    for (int jj = 0; jj < 4; ++jj) res += ord[4*i + jj] * e[jj] * inv;
  }
  out[b] = res;
}

// ---------------------------------------------------------------------------
extern "C" void kernel_launch(void* const* d_in, const int* in_sizes, int n_in,
                              void* d_out, int out_size, void* d_ws, size_t ws_size,
                              hipStream_t stream)
{
  (void)in_sizes; (void)n_in; (void)out_size; (void)ws_size;
  const int*   tids = (const int*)  d_in[0];
  const float* emb  = (const float*)d_in[1];
  const float* fw1  = (const float*)d_in[2];
  const float* fb1  = (const float*)d_in[3];
  const float* fw2  = (const float*)d_in[4];
  const float* fb2  = (const float*)d_in[5];
  const float* attw = (const float*)d_in[6];
  const float* attb = (const float*)d_in[7];
  const float* mw1  = (const float*)d_in[8];
  const float* mb1  = (const float*)d_in[9];
  const float* mw2  = (const float*)d_in[10];
  const float* mb2  = (const float*)d_in[11];
  float* out = (float*)d_out;

  float* H    = (float*)d_ws;                       // 81920*256 f32 = 84 MB
  float* SC   = H + (size_t)NPLAY * PD;             // 327680 f32
  float* PART = SC + NROWS;                         // 8*327680 f32

  k_fm<<<NPLAY/16, 256, 0, stream>>>(tids, emb, fw1, fb1, fw2, fb2, H);
  k_att_score<<<NB/4, 256, 0, stream>>>(H, attw, attb, SC);
  k_mlp<<<dim3(NB/8, 8), 256, 0, stream>>>(H, mw1, mb1, mw2, PART);
  k_final<<<NB/256, 256, 0, stream>>>(SC, PART, mb2, out);
}

// Round 2
// 3149.749 us; speedup vs baseline: 2.5043x; 2.5043x over previous
//
#include <hip/hip_runtime.h>

#define NB     16384
#define TEAM   5
#define NPAIR  20
#define PD     256
#define HD     256
#define H1D    512
#define NPLAY  (NB*TEAM)      // 81920
#define NROWS  (NB*NPAIR)     // 327680
#define NCHUNK 4              // k_mlp column chunks (y-grid)

__device__ __forceinline__ float silu_f(float x){ return x / (1.0f + __expf(-x)); }

// ---------------------------------------------------------------------------
// Kernel A: per 16 players: x = emb[tid]; h1 = silu(W1 x + b1); h = W2 h1 + b2
// LDS: Xs 16x260 (16.6K) + H1s 16x516 (33K) + Ws 256x20 (20.5K) = 70.1K -> 2 blk/CU
// ---------------------------------------------------------------------------
__global__ __launch_bounds__(256,2) void k_fm(
    const int* __restrict__ tids, const float* __restrict__ emb,
    const float* __restrict__ w1, const float* __restrict__ b1,
    const float* __restrict__ w2, const float* __restrict__ b2,
    float* __restrict__ Hout)
{
  __shared__ float Xs[16*260];
  __shared__ float H1s[16*516];
  __shared__ float Ws[256*20];
  const int t   = threadIdx.x;
  const int m0  = blockIdx.x * 16;

  // ---- load X: 16 gathered emb rows, coalesced (16 lanes x float4 per row)
  {
    const int i = t >> 4, l = t & 15;
    const int tid = tids[m0 + i];
    const float* src = emb + (size_t)tid * PD;
    float* dst = Xs + i * 260;
    #pragma unroll
    for (int q = 0; q < 4; ++q) {
      const int c = q * 64 + l * 4;
      *reinterpret_cast<float4*>(dst + c) = *reinterpret_cast<const float4*>(src + c);
    }
  }

  const int rowg = t & 7;    // 0..7  (rows rowg, rowg+8)
  const int colg = t >> 3;   // 0..31 (cols colg + 32j)

  // ---- phase 1: H1 = silu(X @ W1^T + b1), 512 cols in two halves of 256
  for (int half = 0; half < 2; ++half) {
    float acc[2][8];
    #pragma unroll
    for (int i = 0; i < 2; ++i)
      #pragma unroll
      for (int j = 0; j < 8; ++j) acc[i][j] = 0.0f;

    for (int kt = 0; kt < PD; kt += 16) {
      __syncthreads();
      { // stage W1 tile: 256 out-cols x 16 k
        const int n = t >> 2, k4 = (t & 3) * 4;
        #pragma unroll
        for (int pp = 0; pp < 4; ++pp) {
          const int nn = pp * 64 + n;
          *reinterpret_cast<float4*>(Ws + nn * 20 + k4) =
            *reinterpret_cast<const float4*>(w1 + (size_t)(half * 256 + nn) * PD + kt + k4);
        }
      }
      __syncthreads();
      #pragma unroll
      for (int k = 0; k < 16; k += 4) {
        float4 xa[2], wb[8];
        #pragma unroll
        for (int i = 0; i < 2; ++i)
          xa[i] = *reinterpret_cast<const float4*>(Xs + (rowg + 8*i) * 260 + kt + k);
        #pragma unroll
        for (int j = 0; j < 8; ++j)
          wb[j] = *reinterpret_cast<const float4*>(Ws + (colg + 32*j) * 20 + k);
        #pragma unroll
        for (int i = 0; i < 2; ++i)
          #pragma unroll
          for (int j = 0; j < 8; ++j) {
            acc[i][j] = fmaf(xa[i].x, wb[j].x, acc[i][j]);
            acc[i][j] = fmaf(xa[i].y, wb[j].y, acc[i][j]);
            acc[i][j] = fmaf(xa[i].z, wb[j].z, acc[i][j]);
            acc[i][j] = fmaf(xa[i].w, wb[j].w, acc[i][j]);
          }
      }
    }
    // bias + silu -> H1s
    #pragma unroll
    for (int i = 0; i < 2; ++i) {
      const int r = rowg + 8*i;
      #pragma unroll
      for (int j = 0; j < 8; ++j) {
        const int c = colg + 32*j;
        const float v = acc[i][j] + b1[half * 256 + c];
        H1s[r * 516 + half * 256 + c] = silu_f(v);
      }
    }
  }

  // ---- phase 2: H2 = H1 @ W2^T + b2   (K = 512)
  float acc2[2][8];
  #pragma unroll
  for (int i = 0; i < 2; ++i)
    #pragma unroll
    for (int j = 0; j < 8; ++j) acc2[i][j] = 0.0f;

  for (int kt = 0; kt < H1D; kt += 16) {
    __syncthreads();
    { // stage W2 tile: 256 out-cols x 16 k
      const int n = t >> 2, k4 = (t & 3) * 4;
      #pragma unroll
      for (int pp = 0; pp < 4; ++pp) {
        const int nn = pp * 64 + n;
        *reinterpret_cast<float4*>(Ws + nn * 20 + k4) =
          *reinterpret_cast<const float4*>(w2 + (size_t)nn * H1D + kt + k4);
      }
    }
    __syncthreads();
    #pragma unroll
    for (int k = 0; k < 16; k += 4) {
      float4 xa[2], wb[8];
      #pragma unroll
      for (int i = 0; i < 2; ++i)
        xa[i] = *reinterpret_cast<const float4*>(H1s + (rowg + 8*i) * 516 + kt + k);
      #pragma unroll
      for (int j = 0; j < 8; ++j)
        wb[j] = *reinterpret_cast<const float4*>(Ws + (colg + 32*j) * 20 + k);
      #pragma unroll
      for (int i = 0; i < 2; ++i)
        #pragma unroll
        for (int j = 0; j < 8; ++j) {
          acc2[i][j] = fmaf(xa[i].x, wb[j].x, acc2[i][j]);
          acc2[i][j] = fmaf(xa[i].y, wb[j].y, acc2[i][j]);
          acc2[i][j] = fmaf(xa[i].z, wb[j].z, acc2[i][j]);
          acc2[i][j] = fmaf(xa[i].w, wb[j].w, acc2[i][j]);
        }
    }
  }
  __syncthreads();
  // epilogue: +b2, stage into Xs (dead), then coalesced store
  #pragma unroll
  for (int i = 0; i < 2; ++i) {
    const int r = rowg + 8*i;
    #pragma unroll
    for (int j = 0; j < 8; ++j) {
      const int c = colg + 32*j;
      Xs[r * 260 + c] = acc2[i][j] + b2[c];
    }
  }
  __syncthreads();
  #pragma unroll
  for (int q = 0; q < 4; ++q) {
    const int row = q * 4 + (t >> 6);
    const int c4  = (t & 63) * 4;
    *reinterpret_cast<float4*>(Hout + (size_t)(m0 + row) * PD + c4) =
      *reinterpret_cast<const float4*>(Xs + row * 260 + c4);
  }
}

// ---------------------------------------------------------------------------
// Kernel B: per 4 batches (20 players): WA = H @ att_w^T + att_b (kept in LDS),
// then score[b,i,j] = dot(WA[i], H[j]) for the 20 ordered pairs.
// LDS: Hl 20x260 + WAs 20x260 + Ws 256x20 = 62K -> 2 blk/CU
// ---------------------------------------------------------------------------
__global__ __launch_bounds__(256,2) void k_att_score(
    const float* __restrict__ Hin, const float* __restrict__ attw,
    const float* __restrict__ attb, float* __restrict__ SC)
{
  __shared__ float Hl[20*260];
  __shared__ float WAs[20*260];
  __shared__ float Ws[256*20];
  const int t  = threadIdx.x;
  const int b0 = blockIdx.x * 4;

  { // load 20 contiguous player rows
    const float* src = Hin + (size_t)b0 * TEAM * PD;
    const int i = t >> 4, l = t & 15;
    #pragma unroll
    for (int q = 0; q < 4; ++q) {
      const int c = q * 64 + l * 4;
      *reinterpret_cast<float4*>(Hl + i * 260 + c) =
        *reinterpret_cast<const float4*>(src + (size_t)i * PD + c);
    }
    if (t < 64) {
      const int i2 = 16 + (t >> 4), l2 = t & 15;
      #pragma unroll
      for (int q = 0; q < 4; ++q) {
        const int c = q * 64 + l2 * 4;
        *reinterpret_cast<float4*>(Hl + i2 * 260 + c) =
          *reinterpret_cast<const float4*>(src + (size_t)i2 * PD + c);
      }
    }
  }

  const int rowg = t & 3;   // rows rowg + 4i (i=0..4)
  const int colg = t >> 2;  // cols colg + 64j (j=0..3)
  float acc[5][4];
  #pragma unroll
  for (int i = 0; i < 5; ++i)
    #pragma unroll
    for (int j = 0; j < 4; ++j) acc[i][j] = 0.0f;

  for (int kt = 0; kt < HD; kt += 16) {
    __syncthreads();
    { // stage att_w tile
      const int n = t >> 2, k4 = (t & 3) * 4;
      #pragma unroll
      for (int pp = 0; pp < 4; ++pp) {
        const int nn = pp * 64 + n;
        *reinterpret_cast<float4*>(Ws + nn * 20 + k4) =
          *reinterpret_cast<const float4*>(attw + (size_t)nn * HD + kt + k4);
      }
    }
    __syncthreads();
    #pragma unroll
    for (int k = 0; k < 16; k += 4) {
      float4 xa[5], wb[4];
      #pragma unroll
      for (int i = 0; i < 5; ++i)
        xa[i] = *reinterpret_cast<const float4*>(Hl + (rowg + 4*i) * 260 + kt + k);
      #pragma unroll
      for (int j = 0; j < 4; ++j)
        wb[j] = *reinterpret_cast<const float4*>(Ws + (colg + 64*j) * 20 + k);
      #pragma unroll
      for (int i = 0; i < 5; ++i)
        #pragma unroll
        for (int j = 0; j < 4; ++j) {
          acc[i][j] = fmaf(xa[i].x, wb[j].x, acc[i][j]);
          acc[i][j] = fmaf(xa[i].y, wb[j].y, acc[i][j]);
          acc[i][j] = fmaf(xa[i].z, wb[j].z, acc[i][j]);
          acc[i][j] = fmaf(xa[i].w, wb[j].w, acc[i][j]);
        }
    }
  }
  // +att_b -> WAs
  #pragma unroll
  for (int i = 0; i < 5; ++i) {
    const int r = rowg + 4*i;
    #pragma unroll
    for (int j = 0; j < 4; ++j) {
      const int c = colg + 64*j;
      WAs[r * 260 + c] = acc[i][j] + attb[c];
    }
  }
  __syncthreads();

  // score phase: wave w handles batch b0+w; 64 lanes x 4 elems per dot
  {
    const int w = t >> 6, l = t & 63;
    #pragma unroll
    for (int p = 0; p < NPAIR; ++p) {
      const int i1 = p >> 2, jj = p & 3;
      const int i2 = jj + (jj >= i1 ? 1 : 0);
      const float4 a4 = *reinterpret_cast<const float4*>(WAs + (w*TEAM + i1) * 260 + l * 4);
      const float4 b4 = *reinterpret_cast<const float4*>(Hl  + (w*TEAM + i2) * 260 + l * 4);
      float v = a4.x*b4.x + a4.y*b4.y + a4.z*b4.z + a4.w*b4.w;
      #pragma unroll
      for (int off = 32; off > 0; off >>= 1) v += __shfl_xor(v, off);
      if (l == 0) SC[(size_t)(b0 + w) * NPAIR + p] = v;
    }
  }
}

// ---------------------------------------------------------------------------
// Kernel C v2: pair MLP. Block = 8 batches (160 pair rows) x 128 of 512 cols.
// Per-thread tile R=5 x C=16 (acc=80 regs) -> LDS bytes/FMA 1.3 (was 1.8).
// NO __launch_bounds__ second arg (v1's (256,3) drove RA to 84 VGPRs + acc
// spill -> 33 GB of scratch traffic, the round-1 bottleneck).
// red reduction buffer aliases dead Ws -> LDS 51.6 KiB -> 3 blk/CU.
// ---------------------------------------------------------------------------
__global__ __launch_bounds__(256) void k_mlp(
    const float* __restrict__ Hin, const float* __restrict__ w1,
    const float* __restrict__ b1, const float* __restrict__ w2,
    float* __restrict__ PART)
{
  __shared__ float smem[40*260 + 128*20 + 128 + 128];   // 51.63 KiB
  float* Hl = smem;                 // 40 x 260
  float* Ws = smem + 40*260;        // 128 x 20 (k-tile of w1)
  float* Wb = Ws + 128*20;          // 128 bias
  float* Ww = Wb + 128;             // 128 w2
  float* red = Ws;                  // alias: 160x8 reduction, after k-loop

  const int t    = threadIdx.x;
  const int blkx = blockIdx.x;
  const int cy   = blockIdx.y;      // 0..3 -> cols [cy*128, cy*128+128)
  const int b0   = blkx * 8;

  { // load 40 contiguous player rows of H
    const float* src = Hin + (size_t)b0 * TEAM * PD;
    const int i = t >> 4, l = t & 15;
    #pragma unroll
    for (int q = 0; q < 4; ++q) {
      const int c = q * 64 + l * 4;
      *reinterpret_cast<float4*>(Hl + i * 260 + c) =
        *reinterpret_cast<const float4*>(src + (size_t)i * PD + c);
      *reinterpret_cast<float4*>(Hl + (i+16) * 260 + c) =
        *reinterpret_cast<const float4*>(src + (size_t)(i+16) * PD + c);
    }
    if (t < 128) {
      const int i2 = 32 + (t >> 4), l2 = t & 15;
      #pragma unroll
      for (int q = 0; q < 4; ++q) {
        const int c = q * 64 + l2 * 4;
        *reinterpret_cast<float4*>(Hl + i2 * 260 + c) =
          *reinterpret_cast<const float4*>(src + (size_t)i2 * PD + c);
      }
      Wb[t] = b1[cy * 128 + t];
      Ww[t] = w2[cy * 128 + t];
    }
  }

  const int rowg = t & 31;  // rows rowg + 32i (i=0..4)
  const int colg = t >> 5;  // 0..7; cols colg + 8j (j=0..15)

  int oa[5], ob[5];
  #pragma unroll
  for (int i = 0; i < 5; ++i) {
    const int r = rowg + 32*i;
    const int q = r / NPAIR;
    const int p = r - q * NPAIR;
    const int i1 = p >> 2, jj = p & 3;
    const int i2 = jj + (jj >= i1 ? 1 : 0);
    oa[i] = (q * TEAM + i1) * 260;
    ob[i] = (q * TEAM + i2) * 260;
  }

  float acc[5][16];
  #pragma unroll
  for (int i = 0; i < 5; ++i)
    #pragma unroll
    for (int j = 0; j < 16; ++j) acc[i][j] = 0.0f;

  for (int kt = 0; kt < PD; kt += 16) {
    __syncthreads();
    { // stage w1 tile: 128 cols x 16 k = 512 float4, 2 per thread
      #pragma unroll
      for (int pp = 0; pp < 2; ++pp) {
        const int idx = t + pp * 256;
        const int n = idx >> 2, k4 = (idx & 3) * 4;
        *reinterpret_cast<float4*>(Ws + n * 20 + k4) =
          *reinterpret_cast<const float4*>(w1 + (size_t)(cy * 128 + n) * PD + kt + k4);
      }
    }
    __syncthreads();
    #pragma unroll
    for (int k = 0; k < 16; k += 4) {
      float4 pr[5];
      #pragma unroll
      for (int i = 0; i < 5; ++i) {
        const float4 a4 = *reinterpret_cast<const float4*>(Hl + oa[i] + kt + k);
        const float4 b4 = *reinterpret_cast<const float4*>(Hl + ob[i] + kt + k);
        pr[i].x = a4.x * b4.x; pr[i].y = a4.y * b4.y;
        pr[i].z = a4.z * b4.z; pr[i].w = a4.w * b4.w;
      }
      #pragma unroll
      for (int j = 0; j < 16; ++j) {   // one wv live at a time: acc80+pr20+wv4
        const float4 wv = *reinterpret_cast<const float4*>(Ws + (colg + 8*j) * 20 + k);
        #pragma unroll
        for (int i = 0; i < 5; ++i) {
          acc[i][j] = fmaf(pr[i].x, wv.x, acc[i][j]);
          acc[i][j] = fmaf(pr[i].y, wv.y, acc[i][j]);
          acc[i][j] = fmaf(pr[i].z, wv.z, acc[i][j]);
          acc[i][j] = fmaf(pr[i].w, wv.w, acc[i][j]);
        }
      }
    }
  }

  __syncthreads();   // all Ws reads done; safe to reuse as red
  // epilogue: silu + mlp2-dot partial over this block's 128 cols
  #pragma unroll
  for (int i = 0; i < 5; ++i) {
    const int r = rowg + 32*i;
    float s = 0.0f;
    #pragma unroll
    for (int j = 0; j < 16; ++j) {
      const int c = colg + 8*j;
      s += silu_f(acc[i][j] + Wb[c]) * Ww[c];
    }
    red[r * 8 + colg] = s;
  }
  __syncthreads();
  if (t < 160) {
    float s = 0.0f;
    #pragma unroll
    for (int g = 0; g < 8; ++g) s += red[t * 8 + g];
    PART[(size_t)cy * NROWS + (size_t)blkx * 160 + t] = s;
  }
}

// ---------------------------------------------------------------------------
// Kernel D: one thread per batch: order2 = sum(PART)+mlp_b2; softmax(score)
// over each anchor's 4 partners; out[b] = sum order2*normal.
// ---------------------------------------------------------------------------
__global__ void k_final(const float* __restrict__ SC, const float* __restrict__ PART,
                        const float* __restrict__ mb2, float* __restrict__ out)
{
  const int b = blockIdx.x * 256 + threadIdx.x;
  if (b >= NB) return;
  const float bias2 = mb2[0];
  float ord[NPAIR], sc[NPAIR];
  #pragma unroll
  for (int p = 0; p < NPAIR; ++p) {
    float s = bias2;
    #pragma unroll
    for (int g = 0; g < NCHUNK; ++g) s += PART[(size_t)g * NROWS + (size_t)b * NPAIR + p];
    ord[p] = s;
    sc[p] = SC[(size_t)b * NPAIR + p];
  }
  float res = 0.0f;
  #pragma unroll
  for (int i = 0; i < TEAM; ++i) {
    float m = sc[4*i];
    #pragma unroll
    for (int jj = 1; jj < 4; ++jj) m = fmaxf(m, sc[4*i + jj]);
    float e[4], d = 0.0f;
    #pragma unroll
    for (int jj = 0; jj < 4; ++jj) { e[jj] = __expf(sc[4*i + jj] - m); d += e[jj]; }
    const float inv = 1.0f / d;
    #pragma unroll
    for (int jj = 0; jj < 4; ++jj) res += ord[4*i + jj] * e[jj] * inv;
  }
  out[b] = res;
}

// ---------------------------------------------------------------------------
extern "C" void kernel_launch(void* const* d_in, const int* in_sizes, int n_in,
                              void* d_out, int out_size, void* d_ws, size_t ws_size,
                              hipStream_t stream)
{
  (void)in_sizes; (void)n_in; (void)out_size; (void)ws_size;
  const int*   tids = (const int*)  d_in[0];
  const float* emb  = (const float*)d_in[1];
  const float* fw1  = (const float*)d_in[2];
  const float* fb1  = (const float*)d_in[3];
  const float* fw2  = (const float*)d_in[4];
  const float* fb2  = (const float*)d_in[5];
  const float* attw = (const float*)d_in[6];
  const float* attb = (const float*)d_in[7];
  const float* mw1  = (const float*)d_in[8];
  const float* mb1  = (const float*)d_in[9];
  const float* mw2  = (const float*)d_in[10];
  const float* mb2  = (const float*)d_in[11];
  float* out = (float*)d_out;

  float* H    = (float*)d_ws;                       // 81920*256 f32 = 84 MB
  float* SC   = H + (size_t)NPLAY * PD;             // 327680 f32
  float* PART = SC + NROWS;                         // NCHUNK*327680 f32

  k_fm<<<NPLAY/16, 256, 0, stream>>>(tids, emb, fw1, fb1, fw2, fb2, H);
  k_att_score<<<NB/4, 256, 0, stream>>>(H, attw, attb, SC);
  k_mlp<<<dim3(NB/8, NCHUNK), 256, 0, stream>>>(H, mw1, mb1, mw2, PART);
  k_final<<<NB/256, 256, 0, stream>>>(SC, PART, mb2, out);
}

// Round 3
// 1523.458 us; speedup vs baseline: 5.1777x; 2.0675x over previous
//
#include <hip/hip_runtime.h>

#define NB     16384
#define TEAM   5
#define NPAIR  20
#define UPAIR  10             // unordered pairs: prod/order2 are symmetric in (i,j)
#define PD     256
#define HD     256
#define H1D    512
#define NPLAY  (NB*TEAM)      // 81920
#define NCHUNK 4              // k_mlp column chunks (y-grid)

typedef __attribute__((ext_vector_type(4))) float f32x4;
typedef __attribute__((ext_vector_type(8))) short s16x8;

__device__ __forceinline__ float silu_f(float x){ return x / (1.0f + __expf(-x)); }

__device__ __forceinline__ unsigned short bf16_rne(float x){
  unsigned u = __float_as_uint(x);
  unsigned r = u + 0x7fffu + ((u >> 16) & 1u);
  return (unsigned short)(r >> 16);
}
__device__ __forceinline__ float bf16_to_f(unsigned short s){
  return __uint_as_float(((unsigned)s) << 16);
}

// ---------------------------------------------------------------------------
// Kernel A: per 16 players: x = emb[tid]; h1 = silu(W1 x + b1); h = W2 h1 + b2
// (unchanged from round 2)
// ---------------------------------------------------------------------------
__global__ __launch_bounds__(256,2) void k_fm(
    const int* __restrict__ tids, const float* __restrict__ emb,
    const float* __restrict__ w1, const float* __restrict__ b1,
    const float* __restrict__ w2, const float* __restrict__ b2,
    float* __restrict__ Hout)
{
  __shared__ float Xs[16*260];
  __shared__ float H1s[16*516];
  __shared__ float Ws[256*20];
  const int t   = threadIdx.x;
  const int m0  = blockIdx.x * 16;

  {
    const int i = t >> 4, l = t & 15;
    const int tid = tids[m0 + i];
    const float* src = emb + (size_t)tid * PD;
    float* dst = Xs + i * 260;
    #pragma unroll
    for (int q = 0; q < 4; ++q) {
      const int c = q * 64 + l * 4;
      *reinterpret_cast<float4*>(dst + c) = *reinterpret_cast<const float4*>(src + c);
    }
  }

  const int rowg = t & 7;
  const int colg = t >> 3;

  for (int half = 0; half < 2; ++half) {
    float acc[2][8];
    #pragma unroll
    for (int i = 0; i < 2; ++i)
      #pragma unroll
      for (int j = 0; j < 8; ++j) acc[i][j] = 0.0f;

    for (int kt = 0; kt < PD; kt += 16) {
      __syncthreads();
      {
        const int n = t >> 2, k4 = (t & 3) * 4;
        #pragma unroll
        for (int pp = 0; pp < 4; ++pp) {
          const int nn = pp * 64 + n;
          *reinterpret_cast<float4*>(Ws + nn * 20 + k4) =
            *reinterpret_cast<const float4*>(w1 + (size_t)(half * 256 + nn) * PD + kt + k4);
        }
      }
      __syncthreads();
      #pragma unroll
      for (int k = 0; k < 16; k += 4) {
        float4 xa[2], wb[8];
        #pragma unroll
        for (int i = 0; i < 2; ++i)
          xa[i] = *reinterpret_cast<const float4*>(Xs + (rowg + 8*i) * 260 + kt + k);
        #pragma unroll
        for (int j = 0; j < 8; ++j)
          wb[j] = *reinterpret_cast<const float4*>(Ws + (colg + 32*j) * 20 + k);
        #pragma unroll
        for (int i = 0; i < 2; ++i)
          #pragma unroll
          for (int j = 0; j < 8; ++j) {
            acc[i][j] = fmaf(xa[i].x, wb[j].x, acc[i][j]);
            acc[i][j] = fmaf(xa[i].y, wb[j].y, acc[i][j]);
            acc[i][j] = fmaf(xa[i].z, wb[j].z, acc[i][j]);
            acc[i][j] = fmaf(xa[i].w, wb[j].w, acc[i][j]);
          }
      }
    }
    #pragma unroll
    for (int i = 0; i < 2; ++i) {
      const int r = rowg + 8*i;
      #pragma unroll
      for (int j = 0; j < 8; ++j) {
        const int c = colg + 32*j;
        const float v = acc[i][j] + b1[half * 256 + c];
        H1s[r * 516 + half * 256 + c] = silu_f(v);
      }
    }
  }

  float acc2[2][8];
  #pragma unroll
  for (int i = 0; i < 2; ++i)
    #pragma unroll
    for (int j = 0; j < 8; ++j) acc2[i][j] = 0.0f;

  for (int kt = 0; kt < H1D; kt += 16) {
    __syncthreads();
    {
      const int n = t >> 2, k4 = (t & 3) * 4;
      #pragma unroll
      for (int pp = 0; pp < 4; ++pp) {
        const int nn = pp * 64 + n;
        *reinterpret_cast<float4*>(Ws + nn * 20 + k4) =
          *reinterpret_cast<const float4*>(w2 + (size_t)nn * H1D + kt + k4);
      }
    }
    __syncthreads();
    #pragma unroll
    for (int k = 0; k < 16; k += 4) {
      float4 xa[2], wb[8];
      #pragma unroll
      for (int i = 0; i < 2; ++i)
        xa[i] = *reinterpret_cast<const float4*>(H1s + (rowg + 8*i) * 516 + kt + k);
      #pragma unroll
      for (int j = 0; j < 8; ++j)
        wb[j] = *reinterpret_cast<const float4*>(Ws + (colg + 32*j) * 20 + k);
      #pragma unroll
      for (int i = 0; i < 2; ++i)
        #pragma unroll
        for (int j = 0; j < 8; ++j) {
          acc2[i][j] = fmaf(xa[i].x, wb[j].x, acc2[i][j]);
          acc2[i][j] = fmaf(xa[i].y, wb[j].y, acc2[i][j]);
          acc2[i][j] = fmaf(xa[i].z, wb[j].z, acc2[i][j]);
          acc2[i][j] = fmaf(xa[i].w, wb[j].w, acc2[i][j]);
        }
    }
  }
  __syncthreads();
  #pragma unroll
  for (int i = 0; i < 2; ++i) {
    const int r = rowg + 8*i;
    #pragma unroll
    for (int j = 0; j < 8; ++j) {
      const int c = colg + 32*j;
      Xs[r * 260 + c] = acc2[i][j] + b2[c];
    }
  }
  __syncthreads();
  #pragma unroll
  for (int q = 0; q < 4; ++q) {
    const int row = q * 4 + (t >> 6);
    const int c4  = (t & 63) * 4;
    *reinterpret_cast<float4*>(Hout + (size_t)(m0 + row) * PD + c4) =
      *reinterpret_cast<const float4*>(Xs + row * 260 + c4);
  }
}

// ---------------------------------------------------------------------------
// Kernel B: WA = H @ att_w^T + att_b in LDS, then 20 ordered score dots.
// (unchanged from round 2)
// ---------------------------------------------------------------------------
__global__ __launch_bounds__(256,2) void k_att_score(
    const float* __restrict__ Hin, const float* __restrict__ attw,
    const float* __restrict__ attb, float* __restrict__ SC)
{
  __shared__ float Hl[20*260];
  __shared__ float WAs[20*260];
  __shared__ float Ws[256*20];
  const int t  = threadIdx.x;
  const int b0 = blockIdx.x * 4;

  {
    const float* src = Hin + (size_t)b0 * TEAM * PD;
    const int i = t >> 4, l = t & 15;
    #pragma unroll
    for (int q = 0; q < 4; ++q) {
      const int c = q * 64 + l * 4;
      *reinterpret_cast<float4*>(Hl + i * 260 + c) =
        *reinterpret_cast<const float4*>(src + (size_t)i * PD + c);
    }
    if (t < 64) {
      const int i2 = 16 + (t >> 4), l2 = t & 15;
      #pragma unroll
      for (int q = 0; q < 4; ++q) {
        const int c = q * 64 + l2 * 4;
        *reinterpret_cast<float4*>(Hl + i2 * 260 + c) =
          *reinterpret_cast<const float4*>(src + (size_t)i2 * PD + c);
      }
    }
  }

  const int rowg = t & 3;
  const int colg = t >> 2;
  float acc[5][4];
  #pragma unroll
  for (int i = 0; i < 5; ++i)
    #pragma unroll
    for (int j = 0; j < 4; ++j) acc[i][j] = 0.0f;

  for (int kt = 0; kt < HD; kt += 16) {
    __syncthreads();
    {
      const int n = t >> 2, k4 = (t & 3) * 4;
      #pragma unroll
      for (int pp = 0; pp < 4; ++pp) {
        const int nn = pp * 64 + n;
        *reinterpret_cast<float4*>(Ws + nn * 20 + k4) =
          *reinterpret_cast<const float4*>(attw + (size_t)nn * HD + kt + k4);
      }
    }
    __syncthreads();
    #pragma unroll
    for (int k = 0; k < 16; k += 4) {
      float4 xa[5], wb[4];
      #pragma unroll
      for (int i = 0; i < 5; ++i)
        xa[i] = *reinterpret_cast<const float4*>(Hl + (rowg + 4*i) * 260 + kt + k);
      #pragma unroll
      for (int j = 0; j < 4; ++j)
        wb[j] = *reinterpret_cast<const float4*>(Ws + (colg + 64*j) * 20 + k);
      #pragma unroll
      for (int i = 0; i < 5; ++i)
        #pragma unroll
        for (int j = 0; j < 4; ++j) {
          acc[i][j] = fmaf(xa[i].x, wb[j].x, acc[i][j]);
          acc[i][j] = fmaf(xa[i].y, wb[j].y, acc[i][j]);
          acc[i][j] = fmaf(xa[i].z, wb[j].z, acc[i][j]);
          acc[i][j] = fmaf(xa[i].w, wb[j].w, acc[i][j]);
        }
    }
  }
  #pragma unroll
  for (int i = 0; i < 5; ++i) {
    const int r = rowg + 4*i;
    #pragma unroll
    for (int j = 0; j < 4; ++j) {
      const int c = colg + 64*j;
      WAs[r * 260 + c] = acc[i][j] + attb[c];
    }
  }
  __syncthreads();

  {
    const int w = t >> 6, l = t & 63;
    #pragma unroll
    for (int p = 0; p < NPAIR; ++p) {
      const int i1 = p >> 2, jj = p & 3;
      const int i2 = jj + (jj >= i1 ? 1 : 0);
      const float4 a4 = *reinterpret_cast<const float4*>(WAs + (w*TEAM + i1) * 260 + l * 4);
      const float4 b4 = *reinterpret_cast<const float4*>(Hl  + (w*TEAM + i2) * 260 + l * 4);
      float v = a4.x*b4.x + a4.y*b4.y + a4.z*b4.z + a4.w*b4.w;
      #pragma unroll
      for (int off = 32; off > 0; off >>= 1) v += __shfl_xor(v, off);
      if (l == 0) SC[(size_t)(b0 + w) * NPAIR + p] = v;
    }
  }
}

// ---------------------------------------------------------------------------
// Prep: split mlp_w1 into bf16 hi/lo, packed in MFMA B-fragment order:
// w1f[h][nt(32)][kt(8)][lane(64)][slot(8)], element = w1[nt*16+(lane&15)]
// [kt*32+(lane>>4)*8+slot].  131072 shorts per half (512 KB total, L2-resident).
// ---------------------------------------------------------------------------
__global__ void k_split_w1(const float* __restrict__ w1, short* __restrict__ w1f)
{
  const int tid = blockIdx.x * 256 + threadIdx.x;     // 0..131071
  const int slot = tid & 7;
  const int lane = (tid >> 3) & 63;
  const int kt   = (tid >> 9) & 7;
  const int nt   = tid >> 12;
  const int n = nt * 16 + (lane & 15);
  const int k = kt * 32 + ((lane >> 4) << 3) + slot;
  const float v = w1[n * PD + k];
  const unsigned short hi = bf16_rne(v);
  const float lo = v - bf16_to_f(hi);
  w1f[tid]          = (short)hi;
  w1f[131072 + tid] = (short)bf16_rne(lo);
}

// ---------------------------------------------------------------------------
// Kernel C v3: pair MLP on MFMA with split-bf16 (hi*hi + hi*lo + lo*hi).
// Symmetry: only 10 unordered pairs per batch. Block = 8 batches (80 pair
// rows = 5 M-tiles) x 128 cols (8 N-tiles, y-grid 4). A-frags (prod) built
// per-K64-chunk into LDS in frag-packed order; B-frags read from pre-packed
// global w1f (L1/L2-resident). Epilogue fuses silu + mlp_w2 dot via shfl.
// LDS: Hl 41.6K + Af 20.5K + Wb/Ww 1K = 63.1 KiB -> 2 blk/CU.
// ---------------------------------------------------------------------------
__global__ __launch_bounds__(256) void k_mlp(
    const float* __restrict__ Hin, const short* __restrict__ w1f,
    const float* __restrict__ b1, const float* __restrict__ w2,
    float* __restrict__ PART)
{
  __shared__ float Hl[40*260];          // 8 batches x 5 players x 256 (stride 260)
  __shared__ short Af[2*5*2*512];       // [h][mt][ks][lane*8+slot] bf16 frags
  __shared__ float Wb[128];
  __shared__ float Ww[128];

  const int t    = threadIdx.x;
  const int lane = t & 63;
  const int w    = t >> 6;              // wave 0..3
  const int blkx = blockIdx.x;
  const int cy   = blockIdx.y;          // 0..3 -> cols [cy*128, cy*128+128)
  const int b0   = blkx * 8;

  { // load 40 player rows of H (coalesced), + bias/w2 slices
    const float* src = Hin + (size_t)b0 * TEAM * PD;
    #pragma unroll
    for (int rep = 0; rep < 10; ++rep) {
      const int flat = t + rep * 256;   // 0..2559 float4 units
      const int row = flat >> 6, c4 = (flat & 63) * 4;
      *reinterpret_cast<float4*>(Hl + row * 260 + c4) =
        *reinterpret_cast<const float4*>(src + (size_t)row * PD + c4);
    }
    if (t < 128) { Wb[t] = b1[cy * 128 + t]; Ww[t] = w2[cy * 128 + t]; }
  }

  f32x4 acc[5][2];
  #pragma unroll
  for (int mt = 0; mt < 5; ++mt)
    #pragma unroll
    for (int j = 0; j < 2; ++j) acc[mt][j] = (f32x4){0.f,0.f,0.f,0.f};

  const s16x8* Bh = reinterpret_cast<const s16x8*>(w1f);            // [32][8][64]
  const s16x8* Bl = Bh + 32*8*64/ (64/64) / 8 * 8;                  // see below
  // (Bl = second half: 131072 shorts = 16384 s16x8 units)
  Bl = reinterpret_cast<const s16x8*>(w1f + 131072);
  const int nt0 = cy * 8 + w * 2;

  for (int kt = 0; kt < 8; ++kt) {      // 8 K-steps of 32
    const int kc = kt >> 1, ks = kt & 1;
    if (ks == 0) {
      __syncthreads();                  // prev chunk's frag reads done
      // produce A-frags for K64 chunk kc: 1280 groups of 4 elements
      const int kt0 = kc * 64;
      #pragma unroll
      for (int f = 0; f < 5; ++f) {
        const int idx4  = t + f * 256;            // 0..1279
        const int sg    = (idx4 & 1) * 4;         // slot group 0 or 4
        const int lane_ = (idx4 >> 1) & 63;
        const int ks_   = (idx4 >> 7) & 1;
        const int mt_   = idx4 >> 8;              // 0..4
        const int m  = lane_ & 15;
        const int r  = mt_ * 16 + m;              // pair row 0..79
        const int q  = r / UPAIR;                 // batch in block
        const int p  = r - q * UPAIR;             // unordered pair 0..9
        const int i1 = (p >= 4) + (p >= 7) + (p >= 9);
        const int i2 = p - (i1 * (9 - i1)) / 2 + i1 + 1;
        const int kk = kt0 + ks_ * 32 + ((lane_ >> 4) << 3) + sg;
        const float4 a4 = *reinterpret_cast<const float4*>(Hl + (q*TEAM + i1)*260 + kk);
        const float4 b4 = *reinterpret_cast<const float4*>(Hl + (q*TEAM + i2)*260 + kk);
        float pv[4] = {a4.x*b4.x, a4.y*b4.y, a4.z*b4.z, a4.w*b4.w};
        short hi[4], lo[4];
        #pragma unroll
        for (int e = 0; e < 4; ++e) {
          const unsigned short h = bf16_rne(pv[e]);
          hi[e] = (short)h;
          lo[e] = (short)bf16_rne(pv[e] - bf16_to_f(h));
        }
        const int aoff = (mt_ * 2 + ks_) * 512 + lane_ * 8 + sg;
        *reinterpret_cast<short4*>(&Af[aoff])        = make_short4(hi[0],hi[1],hi[2],hi[3]);
        *reinterpret_cast<short4*>(&Af[5120 + aoff]) = make_short4(lo[0],lo[1],lo[2],lo[3]);
      }
      __syncthreads();
    }

    s16x8 ah[5], al[5];
    #pragma unroll
    for (int mt = 0; mt < 5; ++mt) {
      ah[mt] = *reinterpret_cast<const s16x8*>(&Af[(mt*2 + ks)*512 + lane*8]);
      al[mt] = *reinterpret_cast<const s16x8*>(&Af[5120 + (mt*2 + ks)*512 + lane*8]);
    }
    s16x8 bh[2], bl[2];
    #pragma unroll
    for (int j = 0; j < 2; ++j) {
      bh[j] = Bh[((nt0 + j)*8 + kt)*64 + lane];
      bl[j] = Bl[((nt0 + j)*8 + kt)*64 + lane];
    }
    #pragma unroll
    for (int mt = 0; mt < 5; ++mt)
      #pragma unroll
      for (int j = 0; j < 2; ++j) {
        acc[mt][j] = __builtin_amdgcn_mfma_f32_16x16x32_bf16(ah[mt], bh[j], acc[mt][j], 0,0,0);
        acc[mt][j] = __builtin_amdgcn_mfma_f32_16x16x32_bf16(ah[mt], bl[j], acc[mt][j], 0,0,0);
        acc[mt][j] = __builtin_amdgcn_mfma_f32_16x16x32_bf16(al[mt], bh[j], acc[mt][j], 0,0,0);
      }
  }

  __syncthreads();                       // Af reads done; alias as reduction buf
  float* red = reinterpret_cast<float*>(Af);   // 80 rows x 4 waves

  // epilogue: C-layout col=lane&15, row=(lane>>4)*4+r. silu + w2-dot, then
  // shfl-reduce across the 16 lanes holding one row's 16 cols.
  const int colbase = (w * 2) * 16 + (lane & 15);
  #pragma unroll
  for (int mt = 0; mt < 5; ++mt)
    #pragma unroll
    for (int r = 0; r < 4; ++r) {
      float s = 0.0f;
      #pragma unroll
      for (int j = 0; j < 2; ++j) {
        const int c = colbase + j * 16;
        s += silu_f(acc[mt][j][r] + Wb[c]) * Ww[c];
      }
      s += __shfl_xor(s, 1); s += __shfl_xor(s, 2);
      s += __shfl_xor(s, 4); s += __shfl_xor(s, 8);
      if ((lane & 15) == 0) {
        const int row = mt * 16 + ((lane >> 4) << 2) + r;
        red[row * 4 + w] = s;
      }
    }
  __syncthreads();
  if (t < 80) {
    const float s = red[t*4] + red[t*4+1] + red[t*4+2] + red[t*4+3];
    PART[(size_t)cy * (NB*UPAIR) + (size_t)blkx * 80 + t] = s;
  }
}

// ---------------------------------------------------------------------------
// Kernel D: one thread per batch. ord2 over 10 unordered pairs; softmax over
// each anchor's 4 ordered scores; map ordered pair -> unordered ord2.
// ---------------------------------------------------------------------------
__global__ void k_final(const float* __restrict__ SC, const float* __restrict__ PART,
                        const float* __restrict__ mb2, float* __restrict__ out)
{
  const int b = blockIdx.x * 256 + threadIdx.x;
  if (b >= NB) return;
  const float bias2 = mb2[0];
  float ord[UPAIR];
  #pragma unroll
  for (int u = 0; u < UPAIR; ++u) {
    float s = bias2;
    #pragma unroll
    for (int g = 0; g < NCHUNK; ++g) s += PART[(size_t)g * (NB*UPAIR) + (size_t)b * UPAIR + u];
    ord[u] = s;
  }
  float sc[NPAIR];
  #pragma unroll
  for (int p = 0; p < NPAIR; ++p) sc[p] = SC[(size_t)b * NPAIR + p];

  float res = 0.0f;
  #pragma unroll
  for (int i = 0; i < TEAM; ++i) {
    float m = sc[4*i];
    #pragma unroll
    for (int jj = 1; jj < 4; ++jj) m = fmaxf(m, sc[4*i + jj]);
    float e[4], d = 0.0f;
    #pragma unroll
    for (int jj = 0; jj < 4; ++jj) { e[jj] = __expf(sc[4*i + jj] - m); d += e[jj]; }
    const float inv = 1.0f / d;
    #pragma unroll
    for (int jj = 0; jj < 4; ++jj) {
      const int i2 = jj + (jj >= i ? 1 : 0);
      const int a  = i < i2 ? i : i2;
      const int bb = i < i2 ? i2 : i;
      const int u  = (a * (9 - a)) / 2 + (bb - a - 1);
      res += ord[u] * e[jj] * inv;
    }
  }
  out[b] = res;
}

// ---------------------------------------------------------------------------
extern "C" void kernel_launch(void* const* d_in, const int* in_sizes, int n_in,
                              void* d_out, int out_size, void* d_ws, size_t ws_size,
                              hipStream_t stream)
{
  (void)in_sizes; (void)n_in; (void)out_size; (void)ws_size;
  const int*   tids = (const int*)  d_in[0];
  const float* emb  = (const float*)d_in[1];
  const float* fw1  = (const float*)d_in[2];
  const float* fb1  = (const float*)d_in[3];
  const float* fw2  = (const float*)d_in[4];
  const float* fb2  = (const float*)d_in[5];
  const float* attw = (const float*)d_in[6];
  const float* attb = (const float*)d_in[7];
  const float* mw1  = (const float*)d_in[8];
  const float* mb1  = (const float*)d_in[9];
  const float* mw2  = (const float*)d_in[10];
  const float* mb2  = (const float*)d_in[11];
  float* out = (float*)d_out;

  float* H    = (float*)d_ws;                         // 81920*256 f32 = 84 MB
  float* SC   = H + (size_t)NPLAY * PD;               // NB*20 f32
  float* PART = SC + (size_t)NB * NPAIR;              // NCHUNK*NB*10 f32
  short* w1f  = (short*)(PART + (size_t)NCHUNK * NB * UPAIR);  // 2*131072 shorts

  k_split_w1<<<512, 256, 0, stream>>>(mw1, w1f);
  k_fm<<<NPLAY/16, 256, 0, stream>>>(tids, emb, fw1, fb1, fw2, fb2, H);
  k_att_score<<<NB/4, 256, 0, stream>>>(H, attw, attb, SC);
  k_mlp<<<dim3(NB/8, NCHUNK), 256, 0, stream>>>(H, w1f, mb1, mw2, PART);
  k_final<<<NB/256, 256, 0, stream>>>(SC, PART, mb2, out);
}

// Round 4
// 853.391 us; speedup vs baseline: 9.2431x; 1.7852x over previous
//
#include <hip/hip_runtime.h>

#define NB     16384
#define TEAM   5
#define NPAIR  20
#define UPAIR  10             // unordered pairs: prod/order2 are symmetric in (i,j)
#define PD     256
#define HD     256
#define H1D    512
#define NPLAY  (NB*TEAM)      // 81920
#define NCHUNK 4              // k_mlp column chunks (y-grid)

typedef __attribute__((ext_vector_type(4))) float f32x4;
typedef __attribute__((ext_vector_type(8))) short s16x8;

__device__ __forceinline__ float silu_f(float x){ return x / (1.0f + __expf(-x)); }

__device__ __forceinline__ unsigned short bf16_rne(float x){
  unsigned u = __float_as_uint(x);
  unsigned r = u + 0x7fffu + ((u >> 16) & 1u);
  return (unsigned short)(r >> 16);
}
__device__ __forceinline__ float bf16_to_f(unsigned short s){
  return __uint_as_float(((unsigned)s) << 16);
}

// ---------------------------------------------------------------------------
// Generic prep: pack an N x K fp32 row-major matrix into MFMA B-fragment
// order, split bf16 hi/lo:  wf[h][nt][kt][lane][slot8],
// element = w[(nt*16 + (lane&15))*K + kt*32 + (lane>>4)*8 + slot].
// total = N*K elements per half; hi at [0,total), lo at [total, 2*total).
// ---------------------------------------------------------------------------
__global__ void k_pack(const float* __restrict__ w, short* __restrict__ wf,
                       int KT, int total)
{
  const int tid = blockIdx.x * 256 + threadIdx.x;
  if (tid >= total) return;
  const int slot = tid & 7;
  const int lane = (tid >> 3) & 63;
  const int grp  = tid >> 9;
  const int kt   = grp % KT;
  const int nt   = grp / KT;
  const int K    = KT * 32;
  const int n = nt * 16 + (lane & 15);
  const int k = kt * 32 + ((lane >> 4) << 3) + slot;
  const float v = w[(size_t)n * K + k];
  const unsigned short hi = bf16_rne(v);
  const float lo = v - bf16_to_f(hi);
  wf[tid]         = (short)hi;
  wf[total + tid] = (short)bf16_rne(lo);
}

// ---------------------------------------------------------------------------
// Kernel A v2: FM on MFMA with split-bf16. Block = 32 players (2 M-tiles),
// 4 waves. Phase 1: h1 = silu(x@W1^T+b1) (N=512, K=256), x A-frags built
// per-K64-chunk from fp32 LDS. Phase-1 epilogue writes h1 DIRECTLY in
// phase-2 A-frag hi/lo layout (aliases dead x buffer). Phase 2:
// h = h1@W2^T+b2 (N=256, K=512), C-layout store to Hout.
// LDS: union(Xs 33.3K + Af 8K | H1f 64K) + biases 3K = 68.6K -> 2 blk/CU.
// ---------------------------------------------------------------------------
__global__ __launch_bounds__(256) void k_fm2(
    const int* __restrict__ tids, const float* __restrict__ emb,
    const short* __restrict__ w1f, const float* __restrict__ b1,
    const short* __restrict__ w2f, const float* __restrict__ b2,
    float* __restrict__ Hout)
{
  __shared__ char smem[65536 + 3072];
  float* Xs  = reinterpret_cast<float*>(smem);          // 32 x 260 fp32 (phase 1)
  short* Af  = reinterpret_cast<short*>(smem + 40960);  // [hilo][mt2][ks2][512]
  short* H1f = reinterpret_cast<short*>(smem);          // [hilo][16384] (phase 2)
  float* Bb  = reinterpret_cast<float*>(smem + 65536);  // b1[512] b2[256]

  const int t = threadIdx.x, lane = t & 63, w = t >> 6;
  const int m0 = blockIdx.x * 32;

  { // gather 32 emb rows into Xs (8 lanes x float4 per row)
    const int i = t >> 3, l = t & 7;
    const int tid = tids[m0 + i];
    const float* src = emb + (size_t)tid * PD;
    float* dst = Xs + i * 260;
    #pragma unroll
    for (int q = 0; q < 8; ++q) {
      const int c = q * 32 + l * 4;
      *reinterpret_cast<float4*>(dst + c) = *reinterpret_cast<const float4*>(src + c);
    }
    Bb[t]       = b1[t];
    Bb[t + 256] = b1[t + 256];
    Bb[t + 512] = b2[t];
  }

  const s16x8* B1 = reinterpret_cast<const s16x8*>(w1f);   // hi; lo at +16384 units
  const s16x8* B2 = reinterpret_cast<const s16x8*>(w2f);

  // ---------------- phase 1: N=512 (wave w: nt = w*8+j), K=256 ----------------
  f32x4 acc1[2][8];
  #pragma unroll
  for (int mt = 0; mt < 2; ++mt)
    #pragma unroll
    for (int j = 0; j < 8; ++j) acc1[mt][j] = (f32x4){0.f,0.f,0.f,0.f};

  for (int kt = 0; kt < 8; ++kt) {
    const int kc = kt >> 1, ks = kt & 1;
    if (ks == 0) {
      __syncthreads();                 // prev chunk frag reads done / Xs ready
      const int kt0 = kc * 64;
      #pragma unroll
      for (int f = 0; f < 2; ++f) {
        const int idx4  = t + f * 256;            // 0..511 short4 groups per half
        const int sg    = (idx4 & 1) * 4;
        const int lane_ = (idx4 >> 1) & 63;
        const int ks_   = (idx4 >> 7) & 1;
        const int mt_   = idx4 >> 8;              // 0..1
        const int m  = lane_ & 15;
        const int kk = kt0 + ks_ * 32 + ((lane_ >> 4) << 3) + sg;
        const float4 a4 = *reinterpret_cast<const float4*>(Xs + (mt_*16 + m)*260 + kk);
        float pv[4] = {a4.x, a4.y, a4.z, a4.w};
        short hi[4], lo[4];
        #pragma unroll
        for (int e = 0; e < 4; ++e) {
          const unsigned short h = bf16_rne(pv[e]);
          hi[e] = (short)h;
          lo[e] = (short)bf16_rne(pv[e] - bf16_to_f(h));
        }
        const int aoff = (mt_ * 2 + ks_) * 512 + lane_ * 8 + sg;
        *reinterpret_cast<short4*>(&Af[aoff])        = make_short4(hi[0],hi[1],hi[2],hi[3]);
        *reinterpret_cast<short4*>(&Af[2048 + aoff]) = make_short4(lo[0],lo[1],lo[2],lo[3]);
      }
      __syncthreads();
    }

    s16x8 ah[2], al[2];
    #pragma unroll
    for (int mt = 0; mt < 2; ++mt) {
      ah[mt] = *reinterpret_cast<const s16x8*>(&Af[(mt*2 + ks)*512 + lane*8]);
      al[mt] = *reinterpret_cast<const s16x8*>(&Af[2048 + (mt*2 + ks)*512 + lane*8]);
    }
    #pragma unroll
    for (int j = 0; j < 8; ++j) {
      const int nt = w * 8 + j;
      const s16x8 bh = B1[(nt*8 + kt)*64 + lane];
      const s16x8 bl = B1[16384 + (nt*8 + kt)*64 + lane];
      #pragma unroll
      for (int mt = 0; mt < 2; ++mt) {
        acc1[mt][j] = __builtin_amdgcn_mfma_f32_16x16x32_bf16(ah[mt], bh, acc1[mt][j], 0,0,0);
        acc1[mt][j] = __builtin_amdgcn_mfma_f32_16x16x32_bf16(al[mt], bh, acc1[mt][j], 0,0,0);
        acc1[mt][j] = __builtin_amdgcn_mfma_f32_16x16x32_bf16(ah[mt], bl, acc1[mt][j], 0,0,0);
      }
    }
  }

  __syncthreads();   // Xs/Af dead; H1f takes over the union

  // phase-1 epilogue: bias + silu, write h1 as hi/lo bf16 in phase-2 A-frag
  // layout: element (p,k) at [((mt*16 + (k>>5))*64 + (p&15) + 16*((k>>3)&3))*8 + (k&7)]
  #pragma unroll
  for (int mt = 0; mt < 2; ++mt)
    #pragma unroll
    for (int j = 0; j < 8; ++j) {
      const int n     = w * 128 + j * 16 + (lane & 15);
      const int kt2   = n >> 5;
      const int lhalf = 16 * ((n >> 3) & 3);
      const int slot2 = n & 7;
      #pragma unroll
      for (int r = 0; r < 4; ++r) {
        const int prow = ((lane >> 4) << 2) + r;       // p & 15
        const float v = silu_f(acc1[mt][j][r] + Bb[n]);
        const unsigned short hi = bf16_rne(v);
        const int off = ((mt*16 + kt2)*64 + lhalf + prow)*8 + slot2;
        H1f[off]         = (short)hi;
        H1f[16384 + off] = (short)bf16_rne(v - bf16_to_f(hi));
      }
    }
  __syncthreads();

  // ---------------- phase 2: N=256 (wave w: nt = w*4+j), K=512 ----------------
  f32x4 acc2[2][4];
  #pragma unroll
  for (int mt = 0; mt < 2; ++mt)
    #pragma unroll
    for (int j = 0; j < 4; ++j) acc2[mt][j] = (f32x4){0.f,0.f,0.f,0.f};

  for (int kt = 0; kt < 16; ++kt) {
    s16x8 ah[2], al[2];
    #pragma unroll
    for (int mt = 0; mt < 2; ++mt) {
      ah[mt] = *reinterpret_cast<const s16x8*>(&H1f[((mt*16 + kt)*64 + lane)*8]);
      al[mt] = *reinterpret_cast<const s16x8*>(&H1f[16384 + ((mt*16 + kt)*64 + lane)*8]);
    }
    #pragma unroll
    for (int j = 0; j < 4; ++j) {
      const int nt = w * 4 + j;
      const s16x8 bh = B2[(nt*16 + kt)*64 + lane];
      const s16x8 bl = B2[16384 + (nt*16 + kt)*64 + lane];
      #pragma unroll
      for (int mt = 0; mt < 2; ++mt) {
        acc2[mt][j] = __builtin_amdgcn_mfma_f32_16x16x32_bf16(ah[mt], bh, acc2[mt][j], 0,0,0);
        acc2[mt][j] = __builtin_amdgcn_mfma_f32_16x16x32_bf16(al[mt], bh, acc2[mt][j], 0,0,0);
        acc2[mt][j] = __builtin_amdgcn_mfma_f32_16x16x32_bf16(ah[mt], bl, acc2[mt][j], 0,0,0);
      }
    }
  }

  // phase-2 epilogue: +b2, store C-layout direct to Hout (4x64B segs/store)
  #pragma unroll
  for (int mt = 0; mt < 2; ++mt)
    #pragma unroll
    for (int j = 0; j < 4; ++j) {
      const int n = w * 64 + j * 16 + (lane & 15);
      #pragma unroll
      for (int r = 0; r < 4; ++r) {
        const int p = m0 + mt*16 + ((lane >> 4) << 2) + r;
        Hout[(size_t)p * PD + n] = acc2[mt][j][r] + Bb[512 + n];
      }
    }
}

// ---------------------------------------------------------------------------
// Kernel B: WA = H @ att_w^T + att_b in LDS, then 20 ordered score dots.
// (unchanged; fp32 VALU — next round's target)
// ---------------------------------------------------------------------------
__global__ __launch_bounds__(256,2) void k_att_score(
    const float* __restrict__ Hin, const float* __restrict__ attw,
    const float* __restrict__ attb, float* __restrict__ SC)
{
  __shared__ float Hl[20*260];
  __shared__ float WAs[20*260];
  __shared__ float Ws[256*20];
  const int t  = threadIdx.x;
  const int b0 = blockIdx.x * 4;

  {
    const float* src = Hin + (size_t)b0 * TEAM * PD;
    const int i = t >> 4, l = t & 15;
    #pragma unroll
    for (int q = 0; q < 4; ++q) {
      const int c = q * 64 + l * 4;
      *reinterpret_cast<float4*>(Hl + i * 260 + c) =
        *reinterpret_cast<const float4*>(src + (size_t)i * PD + c);
    }
    if (t < 64) {
      const int i2 = 16 + (t >> 4), l2 = t & 15;
      #pragma unroll
      for (int q = 0; q < 4; ++q) {
        const int c = q * 64 + l2 * 4;
        *reinterpret_cast<float4*>(Hl + i2 * 260 + c) =
          *reinterpret_cast<const float4*>(src + (size_t)i2 * PD + c);
      }
    }
  }

  const int rowg = t & 3;
  const int colg = t >> 2;
  float acc[5][4];
  #pragma unroll
  for (int i = 0; i < 5; ++i)
    #pragma unroll
    for (int j = 0; j < 4; ++j) acc[i][j] = 0.0f;

  for (int kt = 0; kt < HD; kt += 16) {
    __syncthreads();
    {
      const int n = t >> 2, k4 = (t & 3) * 4;
      #pragma unroll
      for (int pp = 0; pp < 4; ++pp) {
        const int nn = pp * 64 + n;
        *reinterpret_cast<float4*>(Ws + nn * 20 + k4) =
          *reinterpret_cast<const float4*>(attw + (size_t)nn * HD + kt + k4);
      }
    }
    __syncthreads();
    #pragma unroll
    for (int k = 0; k < 16; k += 4) {
      float4 xa[5], wb[4];
      #pragma unroll
      for (int i = 0; i < 5; ++i)
        xa[i] = *reinterpret_cast<const float4*>(Hl + (rowg + 4*i) * 260 + kt + k);
      #pragma unroll
      for (int j = 0; j < 4; ++j)
        wb[j] = *reinterpret_cast<const float4*>(Ws + (colg + 64*j) * 20 + k);
      #pragma unroll
      for (int i = 0; i < 5; ++i)
        #pragma unroll
        for (int j = 0; j < 4; ++j) {
          acc[i][j] = fmaf(xa[i].x, wb[j].x, acc[i][j]);
          acc[i][j] = fmaf(xa[i].y, wb[j].y, acc[i][j]);
          acc[i][j] = fmaf(xa[i].z, wb[j].z, acc[i][j]);
          acc[i][j] = fmaf(xa[i].w, wb[j].w, acc[i][j]);
        }
    }
  }
  #pragma unroll
  for (int i = 0; i < 5; ++i) {
    const int r = rowg + 4*i;
    #pragma unroll
    for (int j = 0; j < 4; ++j) {
      const int c = colg + 64*j;
      WAs[r * 260 + c] = acc[i][j] + attb[c];
    }
  }
  __syncthreads();

  {
    const int w = t >> 6, l = t & 63;
    #pragma unroll
    for (int p = 0; p < NPAIR; ++p) {
      const int i1 = p >> 2, jj = p & 3;
      const int i2 = jj + (jj >= i1 ? 1 : 0);
      const float4 a4 = *reinterpret_cast<const float4*>(WAs + (w*TEAM + i1) * 260 + l * 4);
      const float4 b4 = *reinterpret_cast<const float4*>(Hl  + (w*TEAM + i2) * 260 + l * 4);
      float v = a4.x*b4.x + a4.y*b4.y + a4.z*b4.z + a4.w*b4.w;
      #pragma unroll
      for (int off = 32; off > 0; off >>= 1) v += __shfl_xor(v, off);
      if (l == 0) SC[(size_t)(b0 + w) * NPAIR + p] = v;
    }
  }
}

// ---------------------------------------------------------------------------
// Kernel C: pair MLP on MFMA with split-bf16 (unchanged from round 3).
// ---------------------------------------------------------------------------
__global__ __launch_bounds__(256) void k_mlp(
    const float* __restrict__ Hin, const short* __restrict__ w1f,
    const float* __restrict__ b1, const float* __restrict__ w2,
    float* __restrict__ PART)
{
  __shared__ float Hl[40*260];
  __shared__ short Af[2*5*2*512];
  __shared__ float Wb[128];
  __shared__ float Ww[128];

  const int t    = threadIdx.x;
  const int lane = t & 63;
  const int w    = t >> 6;
  const int blkx = blockIdx.x;
  const int cy   = blockIdx.y;
  const int b0   = blkx * 8;

  {
    const float* src = Hin + (size_t)b0 * TEAM * PD;
    #pragma unroll
    for (int rep = 0; rep < 10; ++rep) {
      const int flat = t + rep * 256;
      const int row = flat >> 6, c4 = (flat & 63) * 4;
      *reinterpret_cast<float4*>(Hl + row * 260 + c4) =
        *reinterpret_cast<const float4*>(src + (size_t)row * PD + c4);
    }
    if (t < 128) { Wb[t] = b1[cy * 128 + t]; Ww[t] = w2[cy * 128 + t]; }
  }

  f32x4 acc[5][2];
  #pragma unroll
  for (int mt = 0; mt < 5; ++mt)
    #pragma unroll
    for (int j = 0; j < 2; ++j) acc[mt][j] = (f32x4){0.f,0.f,0.f,0.f};

  const s16x8* Bh = reinterpret_cast<const s16x8*>(w1f);
  const s16x8* Bl = reinterpret_cast<const s16x8*>(w1f + 131072);
  const int nt0 = cy * 8 + w * 2;

  for (int kt = 0; kt < 8; ++kt) {
    const int kc = kt >> 1, ks = kt & 1;
    if (ks == 0) {
      __syncthreads();
      const int kt0 = kc * 64;
      #pragma unroll
      for (int f = 0; f < 5; ++f) {
        const int idx4  = t + f * 256;
        const int sg    = (idx4 & 1) * 4;
        const int lane_ = (idx4 >> 1) & 63;
        const int ks_   = (idx4 >> 7) & 1;
        const int mt_   = idx4 >> 8;
        const int m  = lane_ & 15;
        const int r  = mt_ * 16 + m;
        const int q  = r / UPAIR;
        const int p  = r - q * UPAIR;
        const int i1 = (p >= 4) + (p >= 7) + (p >= 9);
        const int i2 = p - (i1 * (9 - i1)) / 2 + i1 + 1;
        const int kk = kt0 + ks_ * 32 + ((lane_ >> 4) << 3) + sg;
        const float4 a4 = *reinterpret_cast<const float4*>(Hl + (q*TEAM + i1)*260 + kk);
        const float4 b4 = *reinterpret_cast<const float4*>(Hl + (q*TEAM + i2)*260 + kk);
        float pv[4] = {a4.x*b4.x, a4.y*b4.y, a4.z*b4.z, a4.w*b4.w};
        short hi[4], lo[4];
        #pragma unroll
        for (int e = 0; e < 4; ++e) {
          const unsigned short h = bf16_rne(pv[e]);
          hi[e] = (short)h;
          lo[e] = (short)bf16_rne(pv[e] - bf16_to_f(h));
        }
        const int aoff = (mt_ * 2 + ks_) * 512 + lane_ * 8 + sg;
        *reinterpret_cast<short4*>(&Af[aoff])        = make_short4(hi[0],hi[1],hi[2],hi[3]);
        *reinterpret_cast<short4*>(&Af[5120 + aoff]) = make_short4(lo[0],lo[1],lo[2],lo[3]);
      }
      __syncthreads();
    }

    s16x8 ah[5], al[5];
    #pragma unroll
    for (int mt = 0; mt < 5; ++mt) {
      ah[mt] = *reinterpret_cast<const s16x8*>(&Af[(mt*2 + ks)*512 + lane*8]);
      al[mt] = *reinterpret_cast<const s16x8*>(&Af[5120 + (mt*2 + ks)*512 + lane*8]);
    }
    s16x8 bh[2], bl[2];
    #pragma unroll
    for (int j = 0; j < 2; ++j) {
      bh[j] = Bh[((nt0 + j)*8 + kt)*64 + lane];
      bl[j] = Bl[((nt0 + j)*8 + kt)*64 + lane];
    }
    #pragma unroll
    for (int mt = 0; mt < 5; ++mt)
      #pragma unroll
      for (int j = 0; j < 2; ++j) {
        acc[mt][j] = __builtin_amdgcn_mfma_f32_16x16x32_bf16(ah[mt], bh[j], acc[mt][j], 0,0,0);
        acc[mt][j] = __builtin_amdgcn_mfma_f32_16x16x32_bf16(ah[mt], bl[j], acc[mt][j], 0,0,0);
        acc[mt][j] = __builtin_amdgcn_mfma_f32_16x16x32_bf16(al[mt], bh[j], acc[mt][j], 0,0,0);
      }
  }

  __syncthreads();
  float* red = reinterpret_cast<float*>(Af);

  const int colbase = (w * 2) * 16 + (lane & 15);
  #pragma unroll
  for (int mt = 0; mt < 5; ++mt)
    #pragma unroll
    for (int r = 0; r < 4; ++r) {
      float s = 0.0f;
      #pragma unroll
      for (int j = 0; j < 2; ++j) {
        const int c = colbase + j * 16;
        s += silu_f(acc[mt][j][r] + Wb[c]) * Ww[c];
      }
      s += __shfl_xor(s, 1); s += __shfl_xor(s, 2);
      s += __shfl_xor(s, 4); s += __shfl_xor(s, 8);
      if ((lane & 15) == 0) {
        const int row = mt * 16 + ((lane >> 4) << 2) + r;
        red[row * 4 + w] = s;
      }
    }
  __syncthreads();
  if (t < 80) {
    const float s = red[t*4] + red[t*4+1] + red[t*4+2] + red[t*4+3];
    PART[(size_t)cy * (NB*UPAIR) + (size_t)blkx * 80 + t] = s;
  }
}

// ---------------------------------------------------------------------------
// Kernel D: one thread per batch (unchanged from round 3).
// ---------------------------------------------------------------------------
__global__ void k_final(const float* __restrict__ SC, const float* __restrict__ PART,
                        const float* __restrict__ mb2, float* __restrict__ out)
{
  const int b = blockIdx.x * 256 + threadIdx.x;
  if (b >= NB) return;
  const float bias2 = mb2[0];
  float ord[UPAIR];
  #pragma unroll
  for (int u = 0; u < UPAIR; ++u) {
    float s = bias2;
    #pragma unroll
    for (int g = 0; g < NCHUNK; ++g) s += PART[(size_t)g * (NB*UPAIR) + (size_t)b * UPAIR + u];
    ord[u] = s;
  }
  float sc[NPAIR];
  #pragma unroll
  for (int p = 0; p < NPAIR; ++p) sc[p] = SC[(size_t)b * NPAIR + p];

  float res = 0.0f;
  #pragma unroll
  for (int i = 0; i < TEAM; ++i) {
    float m = sc[4*i];
    #pragma unroll
    for (int jj = 1; jj < 4; ++jj) m = fmaxf(m, sc[4*i + jj]);
    float e[4], d = 0.0f;
    #pragma unroll
    for (int jj = 0; jj < 4; ++jj) { e[jj] = __expf(sc[4*i + jj] - m); d += e[jj]; }
    const float inv = 1.0f / d;
    #pragma unroll
    for (int jj = 0; jj < 4; ++jj) {
      const int i2 = jj + (jj >= i ? 1 : 0);
      const int a  = i < i2 ? i : i2;
      const int bb = i < i2 ? i2 : i;
      const int u  = (a * (9 - a)) / 2 + (bb - a - 1);
      res += ord[u] * e[jj] * inv;
    }
  }
  out[b] = res;
}

// ---------------------------------------------------------------------------
extern "C" void kernel_launch(void* const* d_in, const int* in_sizes, int n_in,
                              void* d_out, int out_size, void* d_ws, size_t ws_size,
                              hipStream_t stream)
{
  (void)in_sizes; (void)n_in; (void)out_size; (void)ws_size;
  const int*   tids = (const int*)  d_in[0];
  const float* emb  = (const float*)d_in[1];
  const float* fw1  = (const float*)d_in[2];
  const float* fb1  = (const float*)d_in[3];
  const float* fw2  = (const float*)d_in[4];
  const float* fb2  = (const float*)d_in[5];
  const float* attw = (const float*)d_in[6];
  const float* attb = (const float*)d_in[7];
  const float* mw1  = (const float*)d_in[8];
  const float* mb1  = (const float*)d_in[9];
  const float* mw2  = (const float*)d_in[10];
  const float* mb2  = (const float*)d_in[11];
  float* out = (float*)d_out;

  float* H     = (float*)d_ws;                        // 81920*256 f32 = 84 MB
  float* SC    = H + (size_t)NPLAY * PD;              // NB*20 f32
  float* PART  = SC + (size_t)NB * NPAIR;             // NCHUNK*NB*10 f32
  short* w1f_m = (short*)(PART + (size_t)NCHUNK * NB * UPAIR); // mlp_w1 packed
  short* w1f_f = w1f_m + 262144;                      // fm_w1 packed
  short* w2f_f = w1f_f + 262144;                      // fm_w2 packed

  k_pack<<<512, 256, 0, stream>>>(mw1, w1f_m, 8, 131072);   // 512x256
  k_pack<<<512, 256, 0, stream>>>(fw1, w1f_f, 8, 131072);   // 512x256
  k_pack<<<512, 256, 0, stream>>>(fw2, w2f_f, 16, 131072);  // 256x512
  k_fm2<<<NPLAY/32, 256, 0, stream>>>(tids, emb, w1f_f, fb1, w2f_f, fb2, H);
  k_att_score<<<NB/4, 256, 0, stream>>>(H, attw, attb, SC);
  k_mlp<<<dim3(NB/8, NCHUNK), 256, 0, stream>>>(H, w1f_m, mb1, mw2, PART);
  k_final<<<NB/256, 256, 0, stream>>>(SC, PART, mb2, out);
}

// Round 5
// 775.059 us; speedup vs baseline: 10.1772x; 1.1011x over previous
//
#include <hip/hip_runtime.h>

#define NB     16384
#define TEAM   5
#define NPAIR  20
#define UPAIR  10             // unordered pairs: prod/order2 are symmetric in (i,j)
#define PD     256
#define HD     256
#define H1D    512
#define NPLAY  (NB*TEAM)      // 81920
#define NROWS  (NB*NPAIR)
#define NCHUNK 4              // k_mlp column chunks (y-grid)

typedef __attribute__((ext_vector_type(4))) float f32x4;
typedef __attribute__((ext_vector_type(8))) short s16x8;

__device__ __forceinline__ float silu_f(float x){ return x / (1.0f + __expf(-x)); }

__device__ __forceinline__ unsigned short bf16_rne(float x){
  unsigned u = __float_as_uint(x);
  unsigned r = u + 0x7fffu + ((u >> 16) & 1u);
  return (unsigned short)(r >> 16);
}
__device__ __forceinline__ float bf16_to_f(unsigned short s){
  return __uint_as_float(((unsigned)s) << 16);
}

// ---------------------------------------------------------------------------
// Generic prep: pack an N x K fp32 row-major matrix into MFMA B-fragment
// order, split bf16 hi/lo:  wf[h][nt][kt][lane][slot8],
// element = w[(nt*16 + (lane&15))*K + kt*32 + (lane>>4)*8 + slot].
// total = N*K elements per half; hi at [0,total), lo at [total, 2*total).
// ---------------------------------------------------------------------------
__global__ void k_pack(const float* __restrict__ w, short* __restrict__ wf,
                       int KT, int total)
{
  const int tid = blockIdx.x * 256 + threadIdx.x;
  if (tid >= total) return;
  const int slot = tid & 7;
  const int lane = (tid >> 3) & 63;
  const int grp  = tid >> 9;
  const int kt   = grp % KT;
  const int nt   = grp / KT;
  const int K    = KT * 32;
  const int n = nt * 16 + (lane & 15);
  const int k = kt * 32 + ((lane >> 4) << 3) + slot;
  const float v = w[(size_t)n * K + k];
  const unsigned short hi = bf16_rne(v);
  const float lo = v - bf16_to_f(hi);
  wf[tid]         = (short)hi;
  wf[total + tid] = (short)bf16_rne(lo);
}

// ---------------------------------------------------------------------------
// Kernel A v2: FM on MFMA with split-bf16 (unchanged from round 4).
// ---------------------------------------------------------------------------
__global__ __launch_bounds__(256) void k_fm2(
    const int* __restrict__ tids, const float* __restrict__ emb,
    const short* __restrict__ w1f, const float* __restrict__ b1,
    const short* __restrict__ w2f, const float* __restrict__ b2,
    float* __restrict__ Hout)
{
  __shared__ char smem[65536 + 3072];
  float* Xs  = reinterpret_cast<float*>(smem);          // 32 x 260 fp32 (phase 1)
  short* Af  = reinterpret_cast<short*>(smem + 40960);  // [hilo][mt2][ks2][512]
  short* H1f = reinterpret_cast<short*>(smem);          // [hilo][16384] (phase 2)
  float* Bb  = reinterpret_cast<float*>(smem + 65536);  // b1[512] b2[256]

  const int t = threadIdx.x, lane = t & 63, w = t >> 6;
  const int m0 = blockIdx.x * 32;

  { // gather 32 emb rows into Xs (8 lanes x float4 per row)
    const int i = t >> 3, l = t & 7;
    const int tid = tids[m0 + i];
    const float* src = emb + (size_t)tid * PD;
    float* dst = Xs + i * 260;
    #pragma unroll
    for (int q = 0; q < 8; ++q) {
      const int c = q * 32 + l * 4;
      *reinterpret_cast<float4*>(dst + c) = *reinterpret_cast<const float4*>(src + c);
    }
    Bb[t]       = b1[t];
    Bb[t + 256] = b1[t + 256];
    Bb[t + 512] = b2[t];
  }

  const s16x8* B1 = reinterpret_cast<const s16x8*>(w1f);   // hi; lo at +16384 units
  const s16x8* B2 = reinterpret_cast<const s16x8*>(w2f);

  // ---------------- phase 1: N=512 (wave w: nt = w*8+j), K=256 ----------------
  f32x4 acc1[2][8];
  #pragma unroll
  for (int mt = 0; mt < 2; ++mt)
    #pragma unroll
    for (int j = 0; j < 8; ++j) acc1[mt][j] = (f32x4){0.f,0.f,0.f,0.f};

  for (int kt = 0; kt < 8; ++kt) {
    const int kc = kt >> 1, ks = kt & 1;
    if (ks == 0) {
      __syncthreads();
      const int kt0 = kc * 64;
      #pragma unroll
      for (int f = 0; f < 2; ++f) {
        const int idx4  = t + f * 256;
        const int sg    = (idx4 & 1) * 4;
        const int lane_ = (idx4 >> 1) & 63;
        const int ks_   = (idx4 >> 7) & 1;
        const int mt_   = idx4 >> 8;
        const int m  = lane_ & 15;
        const int kk = kt0 + ks_ * 32 + ((lane_ >> 4) << 3) + sg;
        const float4 a4 = *reinterpret_cast<const float4*>(Xs + (mt_*16 + m)*260 + kk);
        float pv[4] = {a4.x, a4.y, a4.z, a4.w};
        short hi[4], lo[4];
        #pragma unroll
        for (int e = 0; e < 4; ++e) {
          const unsigned short h = bf16_rne(pv[e]);
          hi[e] = (short)h;
          lo[e] = (short)bf16_rne(pv[e] - bf16_to_f(h));
        }
        const int aoff = (mt_ * 2 + ks_) * 512 + lane_ * 8 + sg;
        *reinterpret_cast<short4*>(&Af[aoff])        = make_short4(hi[0],hi[1],hi[2],hi[3]);
        *reinterpret_cast<short4*>(&Af[2048 + aoff]) = make_short4(lo[0],lo[1],lo[2],lo[3]);
      }
      __syncthreads();
    }

    s16x8 ah[2], al[2];
    #pragma unroll
    for (int mt = 0; mt < 2; ++mt) {
      ah[mt] = *reinterpret_cast<const s16x8*>(&Af[(mt*2 + ks)*512 + lane*8]);
      al[mt] = *reinterpret_cast<const s16x8*>(&Af[2048 + (mt*2 + ks)*512 + lane*8]);
    }
    #pragma unroll
    for (int j = 0; j < 8; ++j) {
      const int nt = w * 8 + j;
      const s16x8 bh = B1[(nt*8 + kt)*64 + lane];
      const s16x8 bl = B1[16384 + (nt*8 + kt)*64 + lane];
      #pragma unroll
      for (int mt = 0; mt < 2; ++mt) {
        acc1[mt][j] = __builtin_amdgcn_mfma_f32_16x16x32_bf16(ah[mt], bh, acc1[mt][j], 0,0,0);
        acc1[mt][j] = __builtin_amdgcn_mfma_f32_16x16x32_bf16(al[mt], bh, acc1[mt][j], 0,0,0);
        acc1[mt][j] = __builtin_amdgcn_mfma_f32_16x16x32_bf16(ah[mt], bl, acc1[mt][j], 0,0,0);
      }
    }
  }

  __syncthreads();   // Xs/Af dead; H1f takes over the union

  #pragma unroll
  for (int mt = 0; mt < 2; ++mt)
    #pragma unroll
    for (int j = 0; j < 8; ++j) {
      const int n     = w * 128 + j * 16 + (lane & 15);
      const int kt2   = n >> 5;
      const int lhalf = 16 * ((n >> 3) & 3);
      const int slot2 = n & 7;
      #pragma unroll
      for (int r = 0; r < 4; ++r) {
        const int prow = ((lane >> 4) << 2) + r;
        const float v = silu_f(acc1[mt][j][r] + Bb[n]);
        const unsigned short hi = bf16_rne(v);
        const int off = ((mt*16 + kt2)*64 + lhalf + prow)*8 + slot2;
        H1f[off]         = (short)hi;
        H1f[16384 + off] = (short)bf16_rne(v - bf16_to_f(hi));
      }
    }
  __syncthreads();

  // ---------------- phase 2: N=256 (wave w: nt = w*4+j), K=512 ----------------
  f32x4 acc2[2][4];
  #pragma unroll
  for (int mt = 0; mt < 2; ++mt)
    #pragma unroll
    for (int j = 0; j < 4; ++j) acc2[mt][j] = (f32x4){0.f,0.f,0.f,0.f};

  for (int kt = 0; kt < 16; ++kt) {
    s16x8 ah[2], al[2];
    #pragma unroll
    for (int mt = 0; mt < 2; ++mt) {
      ah[mt] = *reinterpret_cast<const s16x8*>(&H1f[((mt*16 + kt)*64 + lane)*8]);
      al[mt] = *reinterpret_cast<const s16x8*>(&H1f[16384 + ((mt*16 + kt)*64 + lane)*8]);
    }
    #pragma unroll
    for (int j = 0; j < 4; ++j) {
      const int nt = w * 4 + j;
      const s16x8 bh = B2[(nt*16 + kt)*64 + lane];
      const s16x8 bl = B2[16384 + (nt*16 + kt)*64 + lane];
      #pragma unroll
      for (int mt = 0; mt < 2; ++mt) {
        acc2[mt][j] = __builtin_amdgcn_mfma_f32_16x16x32_bf16(ah[mt], bh, acc2[mt][j], 0,0,0);
        acc2[mt][j] = __builtin_amdgcn_mfma_f32_16x16x32_bf16(al[mt], bh, acc2[mt][j], 0,0,0);
        acc2[mt][j] = __builtin_amdgcn_mfma_f32_16x16x32_bf16(ah[mt], bl, acc2[mt][j], 0,0,0);
      }
    }
  }

  #pragma unroll
  for (int mt = 0; mt < 2; ++mt)
    #pragma unroll
    for (int j = 0; j < 4; ++j) {
      const int n = w * 64 + j * 16 + (lane & 15);
      #pragma unroll
      for (int r = 0; r < 4; ++r) {
        const int p = m0 + mt*16 + ((lane >> 4) << 2) + r;
        Hout[(size_t)p * PD + n] = acc2[mt][j][r] + Bb[512 + n];
      }
    }
}

// ---------------------------------------------------------------------------
// Kernel B v2: att+score on MFMA split-bf16. Block = 16 batches (80 players,
// 5 M-tiles). Full-K A-frags of H staged hi/lo in LDS (80 KB); B = packed
// att_w from global. WA = H@att_w^T + attb kept in LDS fp32 (aliases the
// dead frag buffer). Score phase: wave w owns 4 batches; dot(WA_i, H_j)
// with the H-side read fp32 straight from global (L2-hot).
// LDS: union(Hf 80K | WAl 83.2K) + attb 1K = 84.2K -> 1 blk/CU (tiny kernel).
// ---------------------------------------------------------------------------
__global__ __launch_bounds__(256) void k_score(
    const float* __restrict__ Hin, const short* __restrict__ attf,
    const float* __restrict__ attb, float* __restrict__ SC)
{
  __shared__ char smem[83200 + 1024];
  short* Hf  = reinterpret_cast<short*>(smem);          // hi [0,20480), lo [20480,40960) shorts
  float* WAl = reinterpret_cast<float*>(smem);          // alias: 80 x 260 fp32
  float* Ab  = reinterpret_cast<float*>(smem + 83200);  // attb[256]

  const int t = threadIdx.x, lane = t & 63, w = t >> 6;
  const int b0 = blockIdx.x * 16;                       // 16 batches per block
  const float* src = Hin + (size_t)b0 * TEAM * PD;      // 80 player rows

  Ab[t] = attb[t];

  // ---- produce full-K (256) A-frags hi/lo for the 80 H rows
  #pragma unroll
  for (int f = 0; f < 20; ++f) {
    const int idx4  = t + f * 256;            // 0..5119 (5mt x 8kt x 64lane x 2sg)
    const int sg    = (idx4 & 1) * 4;
    const int lane_ = (idx4 >> 1) & 63;
    const int kt_   = (idx4 >> 7) & 7;
    const int mt_   = idx4 >> 10;
    const int p = mt_ * 16 + (lane_ & 15);
    const int k = kt_ * 32 + ((lane_ >> 4) << 3) + sg;
    const float4 a4 = *reinterpret_cast<const float4*>(src + (size_t)p * PD + k);
    float pv[4] = {a4.x, a4.y, a4.z, a4.w};
    short hi[4], lo[4];
    #pragma unroll
    for (int e = 0; e < 4; ++e) {
      const unsigned short h = bf16_rne(pv[e]);
      hi[e] = (short)h;
      lo[e] = (short)bf16_rne(pv[e] - bf16_to_f(h));
    }
    const int off = ((mt_*8 + kt_)*64 + lane_)*8 + sg;
    *reinterpret_cast<short4*>(&Hf[off])         = make_short4(hi[0],hi[1],hi[2],hi[3]);
    *reinterpret_cast<short4*>(&Hf[20480 + off]) = make_short4(lo[0],lo[1],lo[2],lo[3]);
  }
  __syncthreads();

  // ---- WA GEMM: M=80, N=256 (wave w: nt = w*4+j), K=256
  f32x4 acc[5][4];
  #pragma unroll
  for (int mt = 0; mt < 5; ++mt)
    #pragma unroll
    for (int j = 0; j < 4; ++j) acc[mt][j] = (f32x4){0.f,0.f,0.f,0.f};

  const s16x8* Bh = reinterpret_cast<const s16x8*>(attf);  // hi [0,8192), lo [8192,16384)
  for (int kt = 0; kt < 8; ++kt) {
    s16x8 ah[5], al[5];
    #pragma unroll
    for (int mt = 0; mt < 5; ++mt) {
      ah[mt] = *reinterpret_cast<const s16x8*>(&Hf[((mt*8 + kt)*64 + lane)*8]);
      al[mt] = *reinterpret_cast<const s16x8*>(&Hf[20480 + ((mt*8 + kt)*64 + lane)*8]);
    }
    #pragma unroll
    for (int j = 0; j < 4; ++j) {
      const int nt = w * 4 + j;
      const s16x8 bh = Bh[(nt*8 + kt)*64 + lane];
      const s16x8 bl = Bh[8192 + (nt*8 + kt)*64 + lane];
      #pragma unroll
      for (int mt = 0; mt < 5; ++mt) {
        acc[mt][j] = __builtin_amdgcn_mfma_f32_16x16x32_bf16(ah[mt], bh, acc[mt][j], 0,0,0);
        acc[mt][j] = __builtin_amdgcn_mfma_f32_16x16x32_bf16(al[mt], bh, acc[mt][j], 0,0,0);
        acc[mt][j] = __builtin_amdgcn_mfma_f32_16x16x32_bf16(ah[mt], bl, acc[mt][j], 0,0,0);
      }
    }
  }
  __syncthreads();   // all Hf reads done; safe to overwrite with WAl

  // ---- WA + attb -> LDS fp32 (C-layout scatter)
  #pragma unroll
  for (int mt = 0; mt < 5; ++mt)
    #pragma unroll
    for (int j = 0; j < 4; ++j) {
      const int n = w * 64 + j * 16 + (lane & 15);
      #pragma unroll
      for (int r = 0; r < 4; ++r) {
        const int row = mt * 16 + ((lane >> 4) << 2) + r;
        WAl[row * 260 + n] = acc[mt][j][r] + Ab[n];
      }
    }
  __syncthreads();

  // ---- score phase: wave w -> batches 4w..4w+3; H-side fp32 from global
  for (int qq = 0; qq < 4; ++qq) {
    const int q = w * 4 + qq;        // local batch 0..15
    #pragma unroll
    for (int p = 0; p < NPAIR; ++p) {
      const int i1 = p >> 2, jj = p & 3;
      const int i2 = jj + (jj >= i1 ? 1 : 0);
      const float4 a4 = *reinterpret_cast<const float4*>(WAl + (q*TEAM + i1) * 260 + lane * 4);
      const float4 b4 = *reinterpret_cast<const float4*>(src + (size_t)(q*TEAM + i2) * PD + lane * 4);
      float v = a4.x*b4.x + a4.y*b4.y + a4.z*b4.z + a4.w*b4.w;
      #pragma unroll
      for (int off = 32; off > 0; off >>= 1) v += __shfl_xor(v, off);
      if (lane == 0) SC[(size_t)(b0 + q) * NPAIR + p] = v;
    }
  }
}

// ---------------------------------------------------------------------------
// Kernel C: pair MLP on MFMA with split-bf16 (unchanged from round 3).
// ---------------------------------------------------------------------------
__global__ __launch_bounds__(256) void k_mlp(
    const float* __restrict__ Hin, const short* __restrict__ w1f,
    const float* __restrict__ b1, const float* __restrict__ w2,
    float* __restrict__ PART)
{
  __shared__ float Hl[40*260];
  __shared__ short Af[2*5*2*512];
  __shared__ float Wb[128];
  __shared__ float Ww[128];

  const int t    = threadIdx.x;
  const int lane = t & 63;
  const int w    = t >> 6;
  const int blkx = blockIdx.x;
  const int cy   = blockIdx.y;
  const int b0   = blkx * 8;

  {
    const float* src = Hin + (size_t)b0 * TEAM * PD;
    #pragma unroll
    for (int rep = 0; rep < 10; ++rep) {
      const int flat = t + rep * 256;
      const int row = flat >> 6, c4 = (flat & 63) * 4;
      *reinterpret_cast<float4*>(Hl + row * 260 + c4) =
        *reinterpret_cast<const float4*>(src + (size_t)row * PD + c4);
    }
    if (t < 128) { Wb[t] = b1[cy * 128 + t]; Ww[t] = w2[cy * 128 + t]; }
  }

  f32x4 acc[5][2];
  #pragma unroll
  for (int mt = 0; mt < 5; ++mt)
    #pragma unroll
    for (int j = 0; j < 2; ++j) acc[mt][j] = (f32x4){0.f,0.f,0.f,0.f};

  const s16x8* Bh = reinterpret_cast<const s16x8*>(w1f);
  const s16x8* Bl = reinterpret_cast<const s16x8*>(w1f + 131072);
  const int nt0 = cy * 8 + w * 2;

  for (int kt = 0; kt < 8; ++kt) {
    const int kc = kt >> 1, ks = kt & 1;
    if (ks == 0) {
      __syncthreads();
      const int kt0 = kc * 64;
      #pragma unroll
      for (int f = 0; f < 5; ++f) {
        const int idx4  = t + f * 256;
        const int sg    = (idx4 & 1) * 4;
        const int lane_ = (idx4 >> 1) & 63;
        const int ks_   = (idx4 >> 7) & 1;
        const int mt_   = idx4 >> 8;
        const int m  = lane_ & 15;
        const int r  = mt_ * 16 + m;
        const int q  = r / UPAIR;
        const int p  = r - q * UPAIR;
        const int i1 = (p >= 4) + (p >= 7) + (p >= 9);
        const int i2 = p - (i1 * (9 - i1)) / 2 + i1 + 1;
        const int kk = kt0 + ks_ * 32 + ((lane_ >> 4) << 3) + sg;
        const float4 a4 = *reinterpret_cast<const float4*>(Hl + (q*TEAM + i1)*260 + kk);
        const float4 b4 = *reinterpret_cast<const float4*>(Hl + (q*TEAM + i2)*260 + kk);
        float pv[4] = {a4.x*b4.x, a4.y*b4.y, a4.z*b4.z, a4.w*b4.w};
        short hi[4], lo[4];
        #pragma unroll
        for (int e = 0; e < 4; ++e) {
          const unsigned short h = bf16_rne(pv[e]);
          hi[e] = (short)h;
          lo[e] = (short)bf16_rne(pv[e] - bf16_to_f(h));
        }
        const int aoff = (mt_ * 2 + ks_) * 512 + lane_ * 8 + sg;
        *reinterpret_cast<short4*>(&Af[aoff])        = make_short4(hi[0],hi[1],hi[2],hi[3]);
        *reinterpret_cast<short4*>(&Af[5120 + aoff]) = make_short4(lo[0],lo[1],lo[2],lo[3]);
      }
      __syncthreads();
    }

    s16x8 ah[5], al[5];
    #pragma unroll
    for (int mt = 0; mt < 5; ++mt) {
      ah[mt] = *reinterpret_cast<const s16x8*>(&Af[(mt*2 + ks)*512 + lane*8]);
      al[mt] = *reinterpret_cast<const s16x8*>(&Af[5120 + (mt*2 + ks)*512 + lane*8]);
    }
    s16x8 bh[2], bl[2];
    #pragma unroll
    for (int j = 0; j < 2; ++j) {
      bh[j] = Bh[((nt0 + j)*8 + kt)*64 + lane];
      bl[j] = Bl[((nt0 + j)*8 + kt)*64 + lane];
    }
    #pragma unroll
    for (int mt = 0; mt < 5; ++mt)
      #pragma unroll
      for (int j = 0; j < 2; ++j) {
        acc[mt][j] = __builtin_amdgcn_mfma_f32_16x16x32_bf16(ah[mt], bh[j], acc[mt][j], 0,0,0);
        acc[mt][j] = __builtin_amdgcn_mfma_f32_16x16x32_bf16(ah[mt], bl[j], acc[mt][j], 0,0,0);
        acc[mt][j] = __builtin_amdgcn_mfma_f32_16x16x32_bf16(al[mt], bh[j], acc[mt][j], 0,0,0);
      }
  }

  __syncthreads();
  float* red = reinterpret_cast<float*>(Af);

  const int colbase = (w * 2) * 16 + (lane & 15);
  #pragma unroll
  for (int mt = 0; mt < 5; ++mt)
    #pragma unroll
    for (int r = 0; r < 4; ++r) {
      float s = 0.0f;
      #pragma unroll
      for (int j = 0; j < 2; ++j) {
        const int c = colbase + j * 16;
        s += silu_f(acc[mt][j][r] + Wb[c]) * Ww[c];
      }
      s += __shfl_xor(s, 1); s += __shfl_xor(s, 2);
      s += __shfl_xor(s, 4); s += __shfl_xor(s, 8);
      if ((lane & 15) == 0) {
        const int row = mt * 16 + ((lane >> 4) << 2) + r;
        red[row * 4 + w] = s;
      }
    }
  __syncthreads();
  if (t < 80) {
    const float s = red[t*4] + red[t*4+1] + red[t*4+2] + red[t*4+3];
    PART[(size_t)cy * (NB*UPAIR) + (size_t)blkx * 80 + t] = s;
  }
}

// ---------------------------------------------------------------------------
// Kernel D: one thread per batch (unchanged from round 3).
// ---------------------------------------------------------------------------
__global__ void k_final(const float* __restrict__ SC, const float* __restrict__ PART,
                        const float* __restrict__ mb2, float* __restrict__ out)
{
  const int b = blockIdx.x * 256 + threadIdx.x;
  if (b >= NB) return;
  const float bias2 = mb2[0];
  float ord[UPAIR];
  #pragma unroll
  for (int u = 0; u < UPAIR; ++u) {
    float s = bias2;
    #pragma unroll
    for (int g = 0; g < NCHUNK; ++g) s += PART[(size_t)g * (NB*UPAIR) + (size_t)b * UPAIR + u];
    ord[u] = s;
  }
  float sc[NPAIR];
  #pragma unroll
  for (int p = 0; p < NPAIR; ++p) sc[p] = SC[(size_t)b * NPAIR + p];

  float res = 0.0f;
  #pragma unroll
  for (int i = 0; i < TEAM; ++i) {
    float m = sc[4*i];
    #pragma unroll
    for (int jj = 1; jj < 4; ++jj) m = fmaxf(m, sc[4*i + jj]);
    float e[4], d = 0.0f;
    #pragma unroll
    for (int jj = 0; jj < 4; ++jj) { e[jj] = __expf(sc[4*i + jj] - m); d += e[jj]; }
    const float inv = 1.0f / d;
    #pragma unroll
    for (int jj = 0; jj < 4; ++jj) {
      const int i2 = jj + (jj >= i ? 1 : 0);
      const int a  = i < i2 ? i : i2;
      const int bb = i < i2 ? i2 : i;
      const int u  = (a * (9 - a)) / 2 + (bb - a - 1);
      res += ord[u] * e[jj] * inv;
    }
  }
  out[b] = res;
}

// ---------------------------------------------------------------------------
extern "C" void kernel_launch(void* const* d_in, const int* in_sizes, int n_in,
                              void* d_out, int out_size, void* d_ws, size_t ws_size,
                              hipStream_t stream)
{
  (void)in_sizes; (void)n_in; (void)out_size; (void)ws_size;
  const int*   tids = (const int*)  d_in[0];
  const float* emb  = (const float*)d_in[1];
  const float* fw1  = (const float*)d_in[2];
  const float* fb1  = (const float*)d_in[3];
  const float* fw2  = (const float*)d_in[4];
  const float* fb2  = (const float*)d_in[5];
  const float* attw = (const float*)d_in[6];
  const float* attb = (const float*)d_in[7];
  const float* mw1  = (const float*)d_in[8];
  const float* mb1  = (const float*)d_in[9];
  const float* mw2  = (const float*)d_in[10];
  const float* mb2  = (const float*)d_in[11];
  float* out = (float*)d_out;

  float* H     = (float*)d_ws;                        // 81920*256 f32 = 84 MB
  float* SC    = H + (size_t)NPLAY * PD;              // NB*20 f32
  float* PART  = SC + (size_t)NB * NPAIR;             // NCHUNK*NB*10 f32
  short* w1f_m = (short*)(PART + (size_t)NCHUNK * NB * UPAIR); // mlp_w1 packed
  short* w1f_f = w1f_m + 262144;                      // fm_w1 packed
  short* w2f_f = w1f_f + 262144;                      // fm_w2 packed
  short* attf  = w2f_f + 262144;                      // att_w packed (131072 shorts)

  k_pack<<<512, 256, 0, stream>>>(mw1, w1f_m, 8, 131072);   // 512x256
  k_pack<<<512, 256, 0, stream>>>(fw1, w1f_f, 8, 131072);   // 512x256
  k_pack<<<512, 256, 0, stream>>>(fw2, w2f_f, 16, 131072);  // 256x512
  k_pack<<<256, 256, 0, stream>>>(attw, attf, 8, 65536);    // 256x256
  k_fm2<<<NPLAY/32, 256, 0, stream>>>(tids, emb, w1f_f, fb1, w2f_f, fb2, H);
  k_score<<<NB/16, 256, 0, stream>>>(H, attf, attb, SC);
  k_mlp<<<dim3(NB/8, NCHUNK), 256, 0, stream>>>(H, w1f_m, mb1, mw2, PART);
  k_final<<<NB/256, 256, 0, stream>>>(SC, PART, mb2, out);
}

// Round 6
// 750.589 us; speedup vs baseline: 10.5090x; 1.0326x over previous
//
#include <hip/hip_runtime.h>

#define NB     16384
#define TEAM   5
#define NPAIR  20
#define UPAIR  10             // unordered pairs: prod/order2 are symmetric in (i,j)
#define PD     256
#define HD     256
#define H1D    512
#define NPLAY  (NB*TEAM)      // 81920
#define NCHUNK 4              // k_mlp column chunks (y-grid)

typedef __attribute__((ext_vector_type(4))) float f32x4;
typedef __attribute__((ext_vector_type(8))) short s16x8;

__device__ __forceinline__ float silu_f(float x){ return x / (1.0f + __expf(-x)); }

__device__ __forceinline__ unsigned short bf16_rne(float x){
  unsigned u = __float_as_uint(x);
  unsigned r = u + 0x7fffu + ((u >> 16) & 1u);
  return (unsigned short)(r >> 16);
}
__device__ __forceinline__ float bf16_to_f(unsigned short s){
  return __uint_as_float(((unsigned)s) << 16);
}

// ---------------------------------------------------------------------------
// Generic prep: pack an N x K fp32 row-major matrix into MFMA B-fragment
// order, split bf16 hi/lo:  wf[h][nt][kt][lane][slot8],
// element = w[(nt*16 + (lane&15))*K + kt*32 + (lane>>4)*8 + slot].
// ---------------------------------------------------------------------------
__global__ void k_pack(const float* __restrict__ w, short* __restrict__ wf,
                       int KT, int total)
{
  const int tid = blockIdx.x * 256 + threadIdx.x;
  if (tid >= total) return;
  const int slot = tid & 7;
  const int lane = (tid >> 3) & 63;
  const int grp  = tid >> 9;
  const int kt   = grp % KT;
  const int nt   = grp / KT;
  const int K    = KT * 32;
  const int n = nt * 16 + (lane & 15);
  const int k = kt * 32 + ((lane >> 4) << 3) + slot;
  const float v = w[(size_t)n * K + k];
  const unsigned short hi = bf16_rne(v);
  const float lo = v - bf16_to_f(hi);
  wf[tid]         = (short)hi;
  wf[total + tid] = (short)bf16_rne(lo);
}

// ---------------------------------------------------------------------------
// Kernel A v3: FM on MFMA, interleaved phases for occupancy.
// Block = 32 players (2 M-tiles). A-frags (x, full K=256, hi/lo) produced
// DIRECTLY from gathered emb (no fp32 staging). Then 4 N-chunks of 128:
// phase-1 partial (h1 cols c*128..+128) -> silu -> 16KB H1c frag buffer ->
// phase-2 partial accumulate (kt2 = c*4+kl). 2 barriers per chunk.
// LDS: Af 32K + H1c 16K + biases 3K = 51K -> 3 blk/CU (was 68.6K -> 2).
// ---------------------------------------------------------------------------
__global__ __launch_bounds__(256) void k_fm3(
    const int* __restrict__ tids, const float* __restrict__ emb,
    const short* __restrict__ w1f, const float* __restrict__ b1,
    const short* __restrict__ w2f, const float* __restrict__ b2,
    float* __restrict__ Hout)
{
  __shared__ char smem[32768 + 16384 + 3072];
  short* Af  = reinterpret_cast<short*>(smem);           // hi [0,8192) lo [8192,16384) shorts
  short* H1c = reinterpret_cast<short*>(smem + 32768);   // hi [0,4096) lo [4096,8192) shorts
  float* Bb  = reinterpret_cast<float*>(smem + 32768 + 16384); // b1[512] b2[256]

  const int t = threadIdx.x, lane = t & 63, w = t >> 6;
  const int m0 = blockIdx.x * 32;

  Bb[t]       = b1[t];
  Bb[t + 256] = b1[t + 256];
  Bb[t + 512] = b2[t];

  // ---- produce full-K A-frags hi/lo for 32 gathered emb rows
  #pragma unroll
  for (int f = 0; f < 8; ++f) {
    const int g     = t + f * 256;           // 0..2047 short4 groups
    const int sg    = (g & 1) * 4;
    const int lane_ = (g >> 1) & 63;
    const int kt_   = (g >> 7) & 7;
    const int mt_   = g >> 10;               // 0..1
    const int p     = mt_ * 16 + (lane_ & 15);
    const int k     = kt_ * 32 + ((lane_ >> 4) << 3) + sg;
    const int row   = tids[m0 + p];
    const float4 a4 = *reinterpret_cast<const float4*>(emb + (size_t)row * PD + k);
    float pv[4] = {a4.x, a4.y, a4.z, a4.w};
    short hi[4], lo[4];
    #pragma unroll
    for (int e = 0; e < 4; ++e) {
      const unsigned short h = bf16_rne(pv[e]);
      hi[e] = (short)h;
      lo[e] = (short)bf16_rne(pv[e] - bf16_to_f(h));
    }
    const int off = ((mt_*8 + kt_)*64 + lane_)*8 + sg;
    *reinterpret_cast<short4*>(&Af[off])        = make_short4(hi[0],hi[1],hi[2],hi[3]);
    *reinterpret_cast<short4*>(&Af[8192 + off]) = make_short4(lo[0],lo[1],lo[2],lo[3]);
  }
  __syncthreads();

  const s16x8* B1 = reinterpret_cast<const s16x8*>(w1f);  // hi; lo at +16384 units
  const s16x8* B2 = reinterpret_cast<const s16x8*>(w2f);

  f32x4 acc2[2][4];
  #pragma unroll
  for (int mt = 0; mt < 2; ++mt)
    #pragma unroll
    for (int j = 0; j < 4; ++j) acc2[mt][j] = (f32x4){0.f,0.f,0.f,0.f};

  for (int c = 0; c < 4; ++c) {
    // ---- phase-1 partial: h1 cols [c*128, c*128+128), wave w: 2 nt
    f32x4 acc1[2][2];
    #pragma unroll
    for (int mt = 0; mt < 2; ++mt)
      #pragma unroll
      for (int j = 0; j < 2; ++j) acc1[mt][j] = (f32x4){0.f,0.f,0.f,0.f};

    for (int kt = 0; kt < 8; ++kt) {
      s16x8 ah[2], al[2];
      #pragma unroll
      for (int mt = 0; mt < 2; ++mt) {
        ah[mt] = *reinterpret_cast<const s16x8*>(&Af[((mt*8 + kt)*64 + lane)*8]);
        al[mt] = *reinterpret_cast<const s16x8*>(&Af[8192 + ((mt*8 + kt)*64 + lane)*8]);
      }
      #pragma unroll
      for (int j = 0; j < 2; ++j) {
        const int nt = c * 8 + w * 2 + j;
        const s16x8 bh = B1[(nt*8 + kt)*64 + lane];
        const s16x8 bl = B1[16384 + (nt*8 + kt)*64 + lane];
        #pragma unroll
        for (int mt = 0; mt < 2; ++mt) {
          acc1[mt][j] = __builtin_amdgcn_mfma_f32_16x16x32_bf16(ah[mt], bh, acc1[mt][j], 0,0,0);
          acc1[mt][j] = __builtin_amdgcn_mfma_f32_16x16x32_bf16(al[mt], bh, acc1[mt][j], 0,0,0);
          acc1[mt][j] = __builtin_amdgcn_mfma_f32_16x16x32_bf16(ah[mt], bl, acc1[mt][j], 0,0,0);
        }
      }
    }

    // ---- epilogue: bias + silu -> H1c in phase-2 A-frag layout (kt2'=w)
    #pragma unroll
    for (int mt = 0; mt < 2; ++mt)
      #pragma unroll
      for (int j = 0; j < 2; ++j) {
        const int nloc  = w * 32 + j * 16 + (lane & 15);   // [0,128)
        const int nglob = c * 128 + nloc;
        const int kt2p  = nloc >> 5;                        // == w
        const int lhalf = 16 * ((nloc >> 3) & 3);
        const int slot2 = nloc & 7;
        #pragma unroll
        for (int r = 0; r < 4; ++r) {
          const int prow = ((lane >> 4) << 2) + r;
          const float v = silu_f(acc1[mt][j][r] + Bb[nglob]);
          const unsigned short hi = bf16_rne(v);
          const int off = ((mt*4 + kt2p)*64 + lhalf + prow)*8 + slot2;
          H1c[off]        = (short)hi;
          H1c[4096 + off] = (short)bf16_rne(v - bf16_to_f(hi));
        }
      }
    __syncthreads();

    // ---- phase-2 partial: kt2 = c*4 + kl, wave w: 4 nt
    #pragma unroll
    for (int kl = 0; kl < 4; ++kl) {
      s16x8 ah[2], al[2];
      #pragma unroll
      for (int mt = 0; mt < 2; ++mt) {
        ah[mt] = *reinterpret_cast<const s16x8*>(&H1c[((mt*4 + kl)*64 + lane)*8]);
        al[mt] = *reinterpret_cast<const s16x8*>(&H1c[4096 + ((mt*4 + kl)*64 + lane)*8]);
      }
      #pragma unroll
      for (int j = 0; j < 4; ++j) {
        const int nt  = w * 4 + j;
        const int kt2 = c * 4 + kl;
        const s16x8 bh = B2[(nt*16 + kt2)*64 + lane];
        const s16x8 bl = B2[16384 + (nt*16 + kt2)*64 + lane];
        #pragma unroll
        for (int mt = 0; mt < 2; ++mt) {
          acc2[mt][j] = __builtin_amdgcn_mfma_f32_16x16x32_bf16(ah[mt], bh, acc2[mt][j], 0,0,0);
          acc2[mt][j] = __builtin_amdgcn_mfma_f32_16x16x32_bf16(al[mt], bh, acc2[mt][j], 0,0,0);
          acc2[mt][j] = __builtin_amdgcn_mfma_f32_16x16x32_bf16(ah[mt], bl, acc2[mt][j], 0,0,0);
        }
      }
    }
    __syncthreads();   // protect H1c before next chunk's epilogue overwrite
  }

  // ---- final epilogue: +b2, C-layout store to Hout
  #pragma unroll
  for (int mt = 0; mt < 2; ++mt)
    #pragma unroll
    for (int j = 0; j < 4; ++j) {
      const int n = w * 64 + j * 16 + (lane & 15);
      #pragma unroll
      for (int r = 0; r < 4; ++r) {
        const int p = m0 + mt*16 + ((lane >> 4) << 2) + r;
        Hout[(size_t)p * PD + n] = acc2[mt][j][r] + Bb[512 + n];
      }
    }
}

// ---------------------------------------------------------------------------
// Kernel B v3: att+score, 8 batches/block (40 rows -> 3 M-tiles, rows 40..47
// zero-padded). LDS: union(Hf 48K | WAl 41.6K) + attb 1K = 49K -> 3 blk/CU
// (v2 was 84K -> 1 blk/CU: the round-5 underperformance).
// ---------------------------------------------------------------------------
__global__ __launch_bounds__(256) void k_score(
    const float* __restrict__ Hin, const short* __restrict__ attf,
    const float* __restrict__ attb, float* __restrict__ SC)
{
  __shared__ char smem[49152 + 1024];
  short* Hf  = reinterpret_cast<short*>(smem);          // hi [0,12288) lo [12288,24576) shorts
  float* WAl = reinterpret_cast<float*>(smem);          // alias: 40 x 260 fp32
  float* Ab  = reinterpret_cast<float*>(smem + 49152);

  const int t = threadIdx.x, lane = t & 63, w = t >> 6;
  const int b0 = blockIdx.x * 8;
  const float* src = Hin + (size_t)b0 * TEAM * PD;      // 40 player rows

  Ab[t] = attb[t];

  // ---- produce full-K A-frags hi/lo for 48 rows (rows >=40 zero)
  #pragma unroll
  for (int f = 0; f < 12; ++f) {
    const int g     = t + f * 256;           // 0..3071
    const int sg    = (g & 1) * 4;
    const int lane_ = (g >> 1) & 63;
    const int kt_   = (g >> 7) & 7;
    const int mt_   = g >> 10;               // 0..2
    const int p     = mt_ * 16 + (lane_ & 15);
    const int k     = kt_ * 32 + ((lane_ >> 4) << 3) + sg;
    float4 a4 = make_float4(0.f, 0.f, 0.f, 0.f);
    if (p < 40) a4 = *reinterpret_cast<const float4*>(src + (size_t)p * PD + k);
    float pv[4] = {a4.x, a4.y, a4.z, a4.w};
    short hi[4], lo[4];
    #pragma unroll
    for (int e = 0; e < 4; ++e) {
      const unsigned short h = bf16_rne(pv[e]);
      hi[e] = (short)h;
      lo[e] = (short)bf16_rne(pv[e] - bf16_to_f(h));
    }
    const int off = ((mt_*8 + kt_)*64 + lane_)*8 + sg;
    *reinterpret_cast<short4*>(&Hf[off])         = make_short4(hi[0],hi[1],hi[2],hi[3]);
    *reinterpret_cast<short4*>(&Hf[12288 + off]) = make_short4(lo[0],lo[1],lo[2],lo[3]);
  }
  __syncthreads();

  // ---- WA GEMM: M=48, N=256 (wave w: nt = w*4+j), K=256
  f32x4 acc[3][4];
  #pragma unroll
  for (int mt = 0; mt < 3; ++mt)
    #pragma unroll
    for (int j = 0; j < 4; ++j) acc[mt][j] = (f32x4){0.f,0.f,0.f,0.f};

  const s16x8* Bh = reinterpret_cast<const s16x8*>(attf);  // hi; lo at +8192 units
  for (int kt = 0; kt < 8; ++kt) {
    s16x8 ah[3], al[3];
    #pragma unroll
    for (int mt = 0; mt < 3; ++mt) {
      ah[mt] = *reinterpret_cast<const s16x8*>(&Hf[((mt*8 + kt)*64 + lane)*8]);
      al[mt] = *reinterpret_cast<const s16x8*>(&Hf[12288 + ((mt*8 + kt)*64 + lane)*8]);
    }
    #pragma unroll
    for (int j = 0; j < 4; ++j) {
      const int nt = w * 4 + j;
      const s16x8 bh = Bh[(nt*8 + kt)*64 + lane];
      const s16x8 bl = Bh[8192 + (nt*8 + kt)*64 + lane];
      #pragma unroll
      for (int mt = 0; mt < 3; ++mt) {
        acc[mt][j] = __builtin_amdgcn_mfma_f32_16x16x32_bf16(ah[mt], bh, acc[mt][j], 0,0,0);
        acc[mt][j] = __builtin_amdgcn_mfma_f32_16x16x32_bf16(al[mt], bh, acc[mt][j], 0,0,0);
        acc[mt][j] = __builtin_amdgcn_mfma_f32_16x16x32_bf16(ah[mt], bl, acc[mt][j], 0,0,0);
      }
    }
  }
  __syncthreads();   // all Hf reads done; safe to overwrite with WAl

  // ---- WA + attb -> LDS fp32 (C-layout scatter), rows < 40 only
  #pragma unroll
  for (int mt = 0; mt < 3; ++mt)
    #pragma unroll
    for (int j = 0; j < 4; ++j) {
      const int n = w * 64 + j * 16 + (lane & 15);
      #pragma unroll
      for (int r = 0; r < 4; ++r) {
        const int row = mt * 16 + ((lane >> 4) << 2) + r;
        if (row < 40) WAl[row * 260 + n] = acc[mt][j][r] + Ab[n];
      }
    }
  __syncthreads();

  // ---- score phase: wave w -> batches w*2, w*2+1; H-side fp32 from global
  #pragma unroll
  for (int qq = 0; qq < 2; ++qq) {
    const int q = w * 2 + qq;        // local batch 0..7
    #pragma unroll
    for (int p = 0; p < NPAIR; ++p) {
      const int i1 = p >> 2, jj = p & 3;
      const int i2 = jj + (jj >= i1 ? 1 : 0);
      const float4 a4 = *reinterpret_cast<const float4*>(WAl + (q*TEAM + i1) * 260 + lane * 4);
      const float4 b4 = *reinterpret_cast<const float4*>(src + (size_t)(q*TEAM + i2) * PD + lane * 4);
      float v = a4.x*b4.x + a4.y*b4.y + a4.z*b4.z + a4.w*b4.w;
      #pragma unroll
      for (int off = 32; off > 0; off >>= 1) v += __shfl_xor(v, off);
      if (lane == 0) SC[(size_t)(b0 + q) * NPAIR + p] = v;
    }
  }
}

// ---------------------------------------------------------------------------
// Kernel C: pair MLP on MFMA with split-bf16 (unchanged from round 3).
// ---------------------------------------------------------------------------
__global__ __launch_bounds__(256) void k_mlp(
    const float* __restrict__ Hin, const short* __restrict__ w1f,
    const float* __restrict__ b1, const float* __restrict__ w2,
    float* __restrict__ PART)
{
  __shared__ float Hl[40*260];
  __shared__ short Af[2*5*2*512];
  __shared__ float Wb[128];
  __shared__ float Ww[128];

  const int t    = threadIdx.x;
  const int lane = t & 63;
  const int w    = t >> 6;
  const int blkx = blockIdx.x;
  const int cy   = blockIdx.y;
  const int b0   = blkx * 8;

  {
    const float* src = Hin + (size_t)b0 * TEAM * PD;
    #pragma unroll
    for (int rep = 0; rep < 10; ++rep) {
      const int flat = t + rep * 256;
      const int row = flat >> 6, c4 = (flat & 63) * 4;
      *reinterpret_cast<float4*>(Hl + row * 260 + c4) =
        *reinterpret_cast<const float4*>(src + (size_t)row * PD + c4);
    }
    if (t < 128) { Wb[t] = b1[cy * 128 + t]; Ww[t] = w2[cy * 128 + t]; }
  }

  f32x4 acc[5][2];
  #pragma unroll
  for (int mt = 0; mt < 5; ++mt)
    #pragma unroll
    for (int j = 0; j < 2; ++j) acc[mt][j] = (f32x4){0.f,0.f,0.f,0.f};

  const s16x8* Bh = reinterpret_cast<const s16x8*>(w1f);
  const s16x8* Bl = reinterpret_cast<const s16x8*>(w1f + 131072);
  const int nt0 = cy * 8 + w * 2;

  for (int kt = 0; kt < 8; ++kt) {
    const int kc = kt >> 1, ks = kt & 1;
    if (ks == 0) {
      __syncthreads();
      const int kt0 = kc * 64;
      #pragma unroll
      for (int f = 0; f < 5; ++f) {
        const int idx4  = t + f * 256;
        const int sg    = (idx4 & 1) * 4;
        const int lane_ = (idx4 >> 1) & 63;
        const int ks_   = (idx4 >> 7) & 1;
        const int mt_   = idx4 >> 8;
        const int m  = lane_ & 15;
        const int r  = mt_ * 16 + m;
        const int q  = r / UPAIR;
        const int p  = r - q * UPAIR;
        const int i1 = (p >= 4) + (p >= 7) + (p >= 9);
        const int i2 = p - (i1 * (9 - i1)) / 2 + i1 + 1;
        const int kk = kt0 + ks_ * 32 + ((lane_ >> 4) << 3) + sg;
        const float4 a4 = *reinterpret_cast<const float4*>(Hl + (q*TEAM + i1)*260 + kk);
        const float4 b4 = *reinterpret_cast<const float4*>(Hl + (q*TEAM + i2)*260 + kk);
        float pv[4] = {a4.x*b4.x, a4.y*b4.y, a4.z*b4.z, a4.w*b4.w};
        short hi[4], lo[4];
        #pragma unroll
        for (int e = 0; e < 4; ++e) {
          const unsigned short h = bf16_rne(pv[e]);
          hi[e] = (short)h;
          lo[e] = (short)bf16_rne(pv[e] - bf16_to_f(h));
        }
        const int aoff = (mt_ * 2 + ks_) * 512 + lane_ * 8 + sg;
        *reinterpret_cast<short4*>(&Af[aoff])        = make_short4(hi[0],hi[1],hi[2],hi[3]);
        *reinterpret_cast<short4*>(&Af[5120 + aoff]) = make_short4(lo[0],lo[1],lo[2],lo[3]);
      }
      __syncthreads();
    }

    s16x8 ah[5], al[5];
    #pragma unroll
    for (int mt = 0; mt < 5; ++mt) {
      ah[mt] = *reinterpret_cast<const s16x8*>(&Af[(mt*2 + ks)*512 + lane*8]);
      al[mt] = *reinterpret_cast<const s16x8*>(&Af[5120 + (mt*2 + ks)*512 + lane*8]);
    }
    s16x8 bh[2], bl[2];
    #pragma unroll
    for (int j = 0; j < 2; ++j) {
      bh[j] = Bh[((nt0 + j)*8 + kt)*64 + lane];
      bl[j] = Bl[((nt0 + j)*8 + kt)*64 + lane];
    }
    #pragma unroll
    for (int mt = 0; mt < 5; ++mt)
      #pragma unroll
      for (int j = 0; j < 2; ++j) {
        acc[mt][j] = __builtin_amdgcn_mfma_f32_16x16x32_bf16(ah[mt], bh[j], acc[mt][j], 0,0,0);
        acc[mt][j] = __builtin_amdgcn_mfma_f32_16x16x32_bf16(ah[mt], bl[j], acc[mt][j], 0,0,0);
        acc[mt][j] = __builtin_amdgcn_mfma_f32_16x16x32_bf16(al[mt], bh[j], acc[mt][j], 0,0,0);
      }
  }

  __syncthreads();
  float* red = reinterpret_cast<float*>(Af);

  const int colbase = (w * 2) * 16 + (lane & 15);
  #pragma unroll
  for (int mt = 0; mt < 5; ++mt)
    #pragma unroll
    for (int r = 0; r < 4; ++r) {
      float s = 0.0f;
      #pragma unroll
      for (int j = 0; j < 2; ++j) {
        const int c = colbase + j * 16;
        s += silu_f(acc[mt][j][r] + Wb[c]) * Ww[c];
      }
      s += __shfl_xor(s, 1); s += __shfl_xor(s, 2);
      s += __shfl_xor(s, 4); s += __shfl_xor(s, 8);
      if ((lane & 15) == 0) {
        const int row = mt * 16 + ((lane >> 4) << 2) + r;
        red[row * 4 + w] = s;
      }
    }
  __syncthreads();
  if (t < 80) {
    const float s = red[t*4] + red[t*4+1] + red[t*4+2] + red[t*4+3];
    PART[(size_t)cy * (NB*UPAIR) + (size_t)blkx * 80 + t] = s;
  }
}

// ---------------------------------------------------------------------------
// Kernel D: one thread per batch (unchanged from round 3).
// ---------------------------------------------------------------------------
__global__ void k_final(const float* __restrict__ SC, const float* __restrict__ PART,
                        const float* __restrict__ mb2, float* __restrict__ out)
{
  const int b = blockIdx.x * 256 + threadIdx.x;
  if (b >= NB) return;
  const float bias2 = mb2[0];
  float ord[UPAIR];
  #pragma unroll
  for (int u = 0; u < UPAIR; ++u) {
    float s = bias2;
    #pragma unroll
    for (int g = 0; g < NCHUNK; ++g) s += PART[(size_t)g * (NB*UPAIR) + (size_t)b * UPAIR + u];
    ord[u] = s;
  }
  float sc[NPAIR];
  #pragma unroll
  for (int p = 0; p < NPAIR; ++p) sc[p] = SC[(size_t)b * NPAIR + p];

  float res = 0.0f;
  #pragma unroll
  for (int i = 0; i < TEAM; ++i) {
    float m = sc[4*i];
    #pragma unroll
    for (int jj = 1; jj < 4; ++jj) m = fmaxf(m, sc[4*i + jj]);
    float e[4], d = 0.0f;
    #pragma unroll
    for (int jj = 0; jj < 4; ++jj) { e[jj] = __expf(sc[4*i + jj] - m); d += e[jj]; }
    const float inv = 1.0f / d;
    #pragma unroll
    for (int jj = 0; jj < 4; ++jj) {
      const int i2 = jj + (jj >= i ? 1 : 0);
      const int a  = i < i2 ? i : i2;
      const int bb = i < i2 ? i2 : i;
      const int u  = (a * (9 - a)) / 2 + (bb - a - 1);
      res += ord[u] * e[jj] * inv;
    }
  }
  out[b] = res;
}

// ---------------------------------------------------------------------------
extern "C" void kernel_launch(void* const* d_in, const int* in_sizes, int n_in,
                              void* d_out, int out_size, void* d_ws, size_t ws_size,
                              hipStream_t stream)
{
  (void)in_sizes; (void)n_in; (void)out_size; (void)ws_size;
  const int*   tids = (const int*)  d_in[0];
  const float* emb  = (const float*)d_in[1];
  const float* fw1  = (const float*)d_in[2];
  const float* fb1  = (const float*)d_in[3];
  const float* fw2  = (const float*)d_in[4];
  const float* fb2  = (const float*)d_in[5];
  const float* attw = (const float*)d_in[6];
  const float* attb = (const float*)d_in[7];
  const float* mw1  = (const float*)d_in[8];
  const float* mb1  = (const float*)d_in[9];
  const float* mw2  = (const float*)d_in[10];
  const float* mb2  = (const float*)d_in[11];
  float* out = (float*)d_out;

  float* H     = (float*)d_ws;                        // 81920*256 f32 = 84 MB
  float* SC    = H + (size_t)NPLAY * PD;              // NB*20 f32
  float* PART  = SC + (size_t)NB * NPAIR;             // NCHUNK*NB*10 f32
  short* w1f_m = (short*)(PART + (size_t)NCHUNK * NB * UPAIR); // mlp_w1 packed
  short* w1f_f = w1f_m + 262144;                      // fm_w1 packed
  short* w2f_f = w1f_f + 262144;                      // fm_w2 packed
  short* attf  = w2f_f + 262144;                      // att_w packed

  k_pack<<<512, 256, 0, stream>>>(mw1, w1f_m, 8, 131072);   // 512x256
  k_pack<<<512, 256, 0, stream>>>(fw1, w1f_f, 8, 131072);   // 512x256
  k_pack<<<512, 256, 0, stream>>>(fw2, w2f_f, 16, 131072);  // 256x512
  k_pack<<<256, 256, 0, stream>>>(attw, attf, 8, 65536);    // 256x256
  k_fm3<<<NPLAY/32, 256, 0, stream>>>(tids, emb, w1f_f, fb1, w2f_f, fb2, H);
  k_score<<<NB/8, 256, 0, stream>>>(H, attf, attb, SC);
  k_mlp<<<dim3(NB/8, NCHUNK), 256, 0, stream>>>(H, w1f_m, mb1, mw2, PART);
  k_final<<<NB/256, 256, 0, stream>>>(SC, PART, mb2, out);
}

// Round 7
// 739.489 us; speedup vs baseline: 10.6668x; 1.0150x over previous
//
#include <hip/hip_runtime.h>

#define NB     16384
#define TEAM   5
#define NPAIR  20
#define UPAIR  10             // unordered pairs: prod/order2 are symmetric in (i,j)
#define PD     256
#define HD     256
#define H1D    512
#define NPLAY  (NB*TEAM)      // 81920
#define NCHUNK 4              // k_mlp column chunks (y-grid)

typedef __attribute__((ext_vector_type(4))) float f32x4;
typedef __attribute__((ext_vector_type(8))) short s16x8;

__device__ __forceinline__ float silu_f(float x){ return x / (1.0f + __expf(-x)); }

__device__ __forceinline__ unsigned short bf16_rne(float x){
  unsigned u = __float_as_uint(x);
  unsigned r = u + 0x7fffu + ((u >> 16) & 1u);
  return (unsigned short)(r >> 16);
}
__device__ __forceinline__ float bf16_to_f(unsigned short s){
  return __uint_as_float(((unsigned)s) << 16);
}

// ---------------------------------------------------------------------------
// Generic prep: pack an N x K fp32 row-major matrix into MFMA B-fragment
// order, split bf16 hi/lo:  wf[h][nt][kt][lane][slot8],
// element = w[(nt*16 + (lane&15))*K + kt*32 + (lane>>4)*8 + slot].
// ---------------------------------------------------------------------------
__global__ void k_pack(const float* __restrict__ w, short* __restrict__ wf,
                       int KT, int total)
{
  const int tid = blockIdx.x * 256 + threadIdx.x;
  if (tid >= total) return;
  const int slot = tid & 7;
  const int lane = (tid >> 3) & 63;
  const int grp  = tid >> 9;
  const int kt   = grp % KT;
  const int nt   = grp / KT;
  const int K    = KT * 32;
  const int n = nt * 16 + (lane & 15);
  const int k = kt * 32 + ((lane >> 4) << 3) + slot;
  const float v = w[(size_t)n * K + k];
  const unsigned short hi = bf16_rne(v);
  const float lo = v - bf16_to_f(hi);
  wf[tid]         = (short)hi;
  wf[total + tid] = (short)bf16_rne(lo);
}

// ---------------------------------------------------------------------------
// Kernel A v4: FM on MFMA. Anti-stall restructure (round-6 lesson: fat MFMA
// batches per iteration beat higher occupancy; barriers drain the pipeline).
// Block = 32 players (2 M-tiles). Full-K A-frags produced ONCE from gathered
// emb (1 barrier). Phase 1: nt=8/wave, 48 MFMA + 16 B-loads per kt, NO
// barriers in K-loop, fully unrolled. H1f (64K) ALIASES dead Af (32K):
// LDS 64K + 3K -> 2 blk/CU, 3 barriers total (was 10).
// ---------------------------------------------------------------------------
__global__ __launch_bounds__(256) void k_fm4(
    const int* __restrict__ tids, const float* __restrict__ emb,
    const short* __restrict__ w1f, const float* __restrict__ b1,
    const short* __restrict__ w2f, const float* __restrict__ b2,
    float* __restrict__ Hout)
{
  __shared__ char smem[65536 + 3072];
  short* Af  = reinterpret_cast<short*>(smem);   // phase1 A: hi [0,8192) lo [8192,16384) shorts
  short* H1f = reinterpret_cast<short*>(smem);   // phase2 A: hi [0,16384) lo [16384,32768) shorts (aliases Af)
  float* Bb  = reinterpret_cast<float*>(smem + 65536); // b1[512] b2[256]

  const int t = threadIdx.x, lane = t & 63, w = t >> 6;
  const int m0 = blockIdx.x * 32;

  Bb[t]       = b1[t];
  Bb[t + 256] = b1[t + 256];
  Bb[t + 512] = b2[t];

  // ---- produce full-K A-frags hi/lo for 32 gathered emb rows (1 barrier)
  #pragma unroll
  for (int f = 0; f < 8; ++f) {
    const int g     = t + f * 256;           // 0..2047 short4 groups
    const int sg    = (g & 1) * 4;
    const int lane_ = (g >> 1) & 63;
    const int kt_   = (g >> 7) & 7;
    const int mt_   = g >> 10;               // 0..1
    const int p     = mt_ * 16 + (lane_ & 15);
    const int k     = kt_ * 32 + ((lane_ >> 4) << 3) + sg;
    const int row   = tids[m0 + p];
    const float4 a4 = *reinterpret_cast<const float4*>(emb + (size_t)row * PD + k);
    float pv[4] = {a4.x, a4.y, a4.z, a4.w};
    short hi[4], lo[4];
    #pragma unroll
    for (int e = 0; e < 4; ++e) {
      const unsigned short h = bf16_rne(pv[e]);
      hi[e] = (short)h;
      lo[e] = (short)bf16_rne(pv[e] - bf16_to_f(h));
    }
    const int off = ((mt_*8 + kt_)*64 + lane_)*8 + sg;
    *reinterpret_cast<short4*>(&Af[off])        = make_short4(hi[0],hi[1],hi[2],hi[3]);
    *reinterpret_cast<short4*>(&Af[8192 + off]) = make_short4(lo[0],lo[1],lo[2],lo[3]);
  }
  __syncthreads();

  const s16x8* B1 = reinterpret_cast<const s16x8*>(w1f);  // hi; lo at +16384 units
  const s16x8* B2 = reinterpret_cast<const s16x8*>(w2f);

  // ---------------- phase 1: N=512 (wave w: nt = w*8+j), K=256 ----------------
  f32x4 acc1[2][8];
  #pragma unroll
  for (int mt = 0; mt < 2; ++mt)
    #pragma unroll
    for (int j = 0; j < 8; ++j) acc1[mt][j] = (f32x4){0.f,0.f,0.f,0.f};

  #pragma unroll
  for (int kt = 0; kt < 8; ++kt) {
    s16x8 ah[2], al[2];
    #pragma unroll
    for (int mt = 0; mt < 2; ++mt) {
      ah[mt] = *reinterpret_cast<const s16x8*>(&Af[((mt*8 + kt)*64 + lane)*8]);
      al[mt] = *reinterpret_cast<const s16x8*>(&Af[8192 + ((mt*8 + kt)*64 + lane)*8]);
    }
    #pragma unroll
    for (int j = 0; j < 8; ++j) {
      const int nt = w * 8 + j;
      const s16x8 bh = B1[(nt*8 + kt)*64 + lane];
      const s16x8 bl = B1[16384 + (nt*8 + kt)*64 + lane];
      #pragma unroll
      for (int mt = 0; mt < 2; ++mt) {
        acc1[mt][j] = __builtin_amdgcn_mfma_f32_16x16x32_bf16(ah[mt], bh, acc1[mt][j], 0,0,0);
        acc1[mt][j] = __builtin_amdgcn_mfma_f32_16x16x32_bf16(al[mt], bh, acc1[mt][j], 0,0,0);
        acc1[mt][j] = __builtin_amdgcn_mfma_f32_16x16x32_bf16(ah[mt], bl, acc1[mt][j], 0,0,0);
      }
    }
  }
  __syncthreads();   // all Af reads done; H1f may overwrite the region

  // ---- epilogue: bias + silu -> H1f in phase-2 A-frag hi/lo layout
  #pragma unroll
  for (int mt = 0; mt < 2; ++mt)
    #pragma unroll
    for (int j = 0; j < 8; ++j) {
      const int n     = w * 128 + j * 16 + (lane & 15);
      const int kt2   = n >> 5;
      const int lhalf = 16 * ((n >> 3) & 3);
      const int slot2 = n & 7;
      #pragma unroll
      for (int r = 0; r < 4; ++r) {
        const int prow = ((lane >> 4) << 2) + r;
        const float v = silu_f(acc1[mt][j][r] + Bb[n]);
        const unsigned short hi = bf16_rne(v);
        const int off = ((mt*16 + kt2)*64 + lhalf + prow)*8 + slot2;
        H1f[off]         = (short)hi;
        H1f[16384 + off] = (short)bf16_rne(v - bf16_to_f(hi));
      }
    }
  __syncthreads();

  // ---------------- phase 2: N=256 (wave w: nt = w*4+j), K=512 ----------------
  f32x4 acc2[2][4];
  #pragma unroll
  for (int mt = 0; mt < 2; ++mt)
    #pragma unroll
    for (int j = 0; j < 4; ++j) acc2[mt][j] = (f32x4){0.f,0.f,0.f,0.f};

  #pragma unroll
  for (int kt = 0; kt < 16; ++kt) {
    s16x8 ah[2], al[2];
    #pragma unroll
    for (int mt = 0; mt < 2; ++mt) {
      ah[mt] = *reinterpret_cast<const s16x8*>(&H1f[((mt*16 + kt)*64 + lane)*8]);
      al[mt] = *reinterpret_cast<const s16x8*>(&H1f[16384 + ((mt*16 + kt)*64 + lane)*8]);
    }
    #pragma unroll
    for (int j = 0; j < 4; ++j) {
      const int nt = w * 4 + j;
      const s16x8 bh = B2[(nt*16 + kt)*64 + lane];
      const s16x8 bl = B2[16384 + (nt*16 + kt)*64 + lane];
      #pragma unroll
      for (int mt = 0; mt < 2; ++mt) {
        acc2[mt][j] = __builtin_amdgcn_mfma_f32_16x16x32_bf16(ah[mt], bh, acc2[mt][j], 0,0,0);
        acc2[mt][j] = __builtin_amdgcn_mfma_f32_16x16x32_bf16(al[mt], bh, acc2[mt][j], 0,0,0);
        acc2[mt][j] = __builtin_amdgcn_mfma_f32_16x16x32_bf16(ah[mt], bl, acc2[mt][j], 0,0,0);
      }
    }
  }

  // ---- final epilogue: +b2, C-layout store to Hout
  #pragma unroll
  for (int mt = 0; mt < 2; ++mt)
    #pragma unroll
    for (int j = 0; j < 4; ++j) {
      const int n = w * 64 + j * 16 + (lane & 15);
      #pragma unroll
      for (int r = 0; r < 4; ++r) {
        const int p = m0 + mt*16 + ((lane >> 4) << 2) + r;
        Hout[(size_t)p * PD + n] = acc2[mt][j][r] + Bb[512 + n];
      }
    }
}

// ---------------------------------------------------------------------------
// Kernel B v3.1: att+score, 8 batches/block (40 rows -> 3 M-tiles, rows
// 40..47 zero-padded). LDS 49K -> 3 blk/CU. kt loop now fully unrolled.
// ---------------------------------------------------------------------------
__global__ __launch_bounds__(256) void k_score(
    const float* __restrict__ Hin, const short* __restrict__ attf,
    const float* __restrict__ attb, float* __restrict__ SC)
{
  __shared__ char smem[49152 + 1024];
  short* Hf  = reinterpret_cast<short*>(smem);          // hi [0,12288) lo [12288,24576) shorts
  float* WAl = reinterpret_cast<float*>(smem);          // alias: 40 x 260 fp32
  float* Ab  = reinterpret_cast<float*>(smem + 49152);

  const int t = threadIdx.x, lane = t & 63, w = t >> 6;
  const int b0 = blockIdx.x * 8;
  const float* src = Hin + (size_t)b0 * TEAM * PD;      // 40 player rows

  Ab[t] = attb[t];

  // ---- produce full-K A-frags hi/lo for 48 rows (rows >=40 zero)
  #pragma unroll
  for (int f = 0; f < 12; ++f) {
    const int g     = t + f * 256;           // 0..3071
    const int sg    = (g & 1) * 4;
    const int lane_ = (g >> 1) & 63;
    const int kt_   = (g >> 7) & 7;
    const int mt_   = g >> 10;               // 0..2
    const int p     = mt_ * 16 + (lane_ & 15);
    const int k     = kt_ * 32 + ((lane_ >> 4) << 3) + sg;
    float4 a4 = make_float4(0.f, 0.f, 0.f, 0.f);
    if (p < 40) a4 = *reinterpret_cast<const float4*>(src + (size_t)p * PD + k);
    float pv[4] = {a4.x, a4.y, a4.z, a4.w};
    short hi[4], lo[4];
    #pragma unroll
    for (int e = 0; e < 4; ++e) {
      const unsigned short h = bf16_rne(pv[e]);
      hi[e] = (short)h;
      lo[e] = (short)bf16_rne(pv[e] - bf16_to_f(h));
    }
    const int off = ((mt_*8 + kt_)*64 + lane_)*8 + sg;
    *reinterpret_cast<short4*>(&Hf[off])         = make_short4(hi[0],hi[1],hi[2],hi[3]);
    *reinterpret_cast<short4*>(&Hf[12288 + off]) = make_short4(lo[0],lo[1],lo[2],lo[3]);
  }
  __syncthreads();

  // ---- WA GEMM: M=48, N=256 (wave w: nt = w*4+j), K=256
  f32x4 acc[3][4];
  #pragma unroll
  for (int mt = 0; mt < 3; ++mt)
    #pragma unroll
    for (int j = 0; j < 4; ++j) acc[mt][j] = (f32x4){0.f,0.f,0.f,0.f};

  const s16x8* Bh = reinterpret_cast<const s16x8*>(attf);  // hi; lo at +8192 units
  #pragma unroll
  for (int kt = 0; kt < 8; ++kt) {
    s16x8 ah[3], al[3];
    #pragma unroll
    for (int mt = 0; mt < 3; ++mt) {
      ah[mt] = *reinterpret_cast<const s16x8*>(&Hf[((mt*8 + kt)*64 + lane)*8]);
      al[mt] = *reinterpret_cast<const s16x8*>(&Hf[12288 + ((mt*8 + kt)*64 + lane)*8]);
    }
    #pragma unroll
    for (int j = 0; j < 4; ++j) {
      const int nt = w * 4 + j;
      const s16x8 bh = Bh[(nt*8 + kt)*64 + lane];
      const s16x8 bl = Bh[8192 + (nt*8 + kt)*64 + lane];
      #pragma unroll
      for (int mt = 0; mt < 3; ++mt) {
        acc[mt][j] = __builtin_amdgcn_mfma_f32_16x16x32_bf16(ah[mt], bh, acc[mt][j], 0,0,0);
        acc[mt][j] = __builtin_amdgcn_mfma_f32_16x16x32_bf16(al[mt], bh, acc[mt][j], 0,0,0);
        acc[mt][j] = __builtin_amdgcn_mfma_f32_16x16x32_bf16(ah[mt], bl, acc[mt][j], 0,0,0);
      }
    }
  }
  __syncthreads();   // all Hf reads done; safe to overwrite with WAl

  // ---- WA + attb -> LDS fp32 (C-layout scatter), rows < 40 only
  #pragma unroll
  for (int mt = 0; mt < 3; ++mt)
    #pragma unroll
    for (int j = 0; j < 4; ++j) {
      const int n = w * 64 + j * 16 + (lane & 15);
      #pragma unroll
      for (int r = 0; r < 4; ++r) {
        const int row = mt * 16 + ((lane >> 4) << 2) + r;
        if (row < 40) WAl[row * 260 + n] = acc[mt][j][r] + Ab[n];
      }
    }
  __syncthreads();

  // ---- score phase: wave w -> batches w*2, w*2+1; H-side fp32 from global
  #pragma unroll
  for (int qq = 0; qq < 2; ++qq) {
    const int q = w * 2 + qq;        // local batch 0..7
    #pragma unroll
    for (int p = 0; p < NPAIR; ++p) {
      const int i1 = p >> 2, jj = p & 3;
      const int i2 = jj + (jj >= i1 ? 1 : 0);
      const float4 a4 = *reinterpret_cast<const float4*>(WAl + (q*TEAM + i1) * 260 + lane * 4);
      const float4 b4 = *reinterpret_cast<const float4*>(src + (size_t)(q*TEAM + i2) * PD + lane * 4);
      float v = a4.x*b4.x + a4.y*b4.y + a4.z*b4.z + a4.w*b4.w;
      #pragma unroll
      for (int off = 32; off > 0; off >>= 1) v += __shfl_xor(v, off);
      if (lane == 0) SC[(size_t)(b0 + q) * NPAIR + p] = v;
    }
  }
}

// ---------------------------------------------------------------------------
// Kernel C: pair MLP on MFMA with split-bf16 (unchanged from round 3).
// ---------------------------------------------------------------------------
__global__ __launch_bounds__(256) void k_mlp(
    const float* __restrict__ Hin, const short* __restrict__ w1f,
    const float* __restrict__ b1, const float* __restrict__ w2,
    float* __restrict__ PART)
{
  __shared__ float Hl[40*260];
  __shared__ short Af[2*5*2*512];
  __shared__ float Wb[128];
  __shared__ float Ww[128];

  const int t    = threadIdx.x;
  const int lane = t & 63;
  const int w    = t >> 6;
  const int blkx = blockIdx.x;
  const int cy   = blockIdx.y;
  const int b0   = blkx * 8;

  {
    const float* src = Hin + (size_t)b0 * TEAM * PD;
    #pragma unroll
    for (int rep = 0; rep < 10; ++rep) {
      const int flat = t + rep * 256;
      const int row = flat >> 6, c4 = (flat & 63) * 4;
      *reinterpret_cast<float4*>(Hl + row * 260 + c4) =
        *reinterpret_cast<const float4*>(src + (size_t)row * PD + c4);
    }
    if (t < 128) { Wb[t] = b1[cy * 128 + t]; Ww[t] = w2[cy * 128 + t]; }
  }

  f32x4 acc[5][2];
  #pragma unroll
  for (int mt = 0; mt < 5; ++mt)
    #pragma unroll
    for (int j = 0; j < 2; ++j) acc[mt][j] = (f32x4){0.f,0.f,0.f,0.f};

  const s16x8* Bh = reinterpret_cast<const s16x8*>(w1f);
  const s16x8* Bl = reinterpret_cast<const s16x8*>(w1f + 131072);
  const int nt0 = cy * 8 + w * 2;

  for (int kt = 0; kt < 8; ++kt) {
    const int kc = kt >> 1, ks = kt & 1;
    if (ks == 0) {
      __syncthreads();
      const int kt0 = kc * 64;
      #pragma unroll
      for (int f = 0; f < 5; ++f) {
        const int idx4  = t + f * 256;
        const int sg    = (idx4 & 1) * 4;
        const int lane_ = (idx4 >> 1) & 63;
        const int ks_   = (idx4 >> 7) & 1;
        const int mt_   = idx4 >> 8;
        const int m  = lane_ & 15;
        const int r  = mt_ * 16 + m;
        const int q  = r / UPAIR;
        const int p  = r - q * UPAIR;
        const int i1 = (p >= 4) + (p >= 7) + (p >= 9);
        const int i2 = p - (i1 * (9 - i1)) / 2 + i1 + 1;
        const int kk = kt0 + ks_ * 32 + ((lane_ >> 4) << 3) + sg;
        const float4 a4 = *reinterpret_cast<const float4*>(Hl + (q*TEAM + i1)*260 + kk);
        const float4 b4 = *reinterpret_cast<const float4*>(Hl + (q*TEAM + i2)*260 + kk);
        float pv[4] = {a4.x*b4.x, a4.y*b4.y, a4.z*b4.z, a4.w*b4.w};
        short hi[4], lo[4];
        #pragma unroll
        for (int e = 0; e < 4; ++e) {
          const unsigned short h = bf16_rne(pv[e]);
          hi[e] = (short)h;
          lo[e] = (short)bf16_rne(pv[e] - bf16_to_f(h));
        }
        const int aoff = (mt_ * 2 + ks_) * 512 + lane_ * 8 + sg;
        *reinterpret_cast<short4*>(&Af[aoff])        = make_short4(hi[0],hi[1],hi[2],hi[3]);
        *reinterpret_cast<short4*>(&Af[5120 + aoff]) = make_short4(lo[0],lo[1],lo[2],lo[3]);
      }
      __syncthreads();
    }

    s16x8 ah[5], al[5];
    #pragma unroll
    for (int mt = 0; mt < 5; ++mt) {
      ah[mt] = *reinterpret_cast<const s16x8*>(&Af[(mt*2 + ks)*512 + lane*8]);
      al[mt] = *reinterpret_cast<const s16x8*>(&Af[5120 + (mt*2 + ks)*512 + lane*8]);
    }
    s16x8 bh[2], bl[2];
    #pragma unroll
    for (int j = 0; j < 2; ++j) {
      bh[j] = Bh[((nt0 + j)*8 + kt)*64 + lane];
      bl[j] = Bl[((nt0 + j)*8 + kt)*64 + lane];
    }
    #pragma unroll
    for (int mt = 0; mt < 5; ++mt)
      #pragma unroll
      for (int j = 0; j < 2; ++j) {
        acc[mt][j] = __builtin_amdgcn_mfma_f32_16x16x32_bf16(ah[mt], bh[j], acc[mt][j], 0,0,0);
        acc[mt][j] = __builtin_amdgcn_mfma_f32_16x16x32_bf16(ah[mt], bl[j], acc[mt][j], 0,0,0);
        acc[mt][j] = __builtin_amdgcn_mfma_f32_16x16x32_bf16(al[mt], bh[j], acc[mt][j], 0,0,0);
      }
  }

  __syncthreads();
  float* red = reinterpret_cast<float*>(Af);

  const int colbase = (w * 2) * 16 + (lane & 15);
  #pragma unroll
  for (int mt = 0; mt < 5; ++mt)
    #pragma unroll
    for (int r = 0; r < 4; ++r) {
      float s = 0.0f;
      #pragma unroll
      for (int j = 0; j < 2; ++j) {
        const int c = colbase + j * 16;
        s += silu_f(acc[mt][j][r] + Wb[c]) * Ww[c];
      }
      s += __shfl_xor(s, 1); s += __shfl_xor(s, 2);
      s += __shfl_xor(s, 4); s += __shfl_xor(s, 8);
      if ((lane & 15) == 0) {
        const int row = mt * 16 + ((lane >> 4) << 2) + r;
        red[row * 4 + w] = s;
      }
    }
  __syncthreads();
  if (t < 80) {
    const float s = red[t*4] + red[t*4+1] + red[t*4+2] + red[t*4+3];
    PART[(size_t)cy * (NB*UPAIR) + (size_t)blkx * 80 + t] = s;
  }
}

// ---------------------------------------------------------------------------
// Kernel D: one thread per batch (unchanged from round 3).
// ---------------------------------------------------------------------------
__global__ void k_final(const float* __restrict__ SC, const float* __restrict__ PART,
                        const float* __restrict__ mb2, float* __restrict__ out)
{
  const int b = blockIdx.x * 256 + threadIdx.x;
  if (b >= NB) return;
  const float bias2 = mb2[0];
  float ord[UPAIR];
  #pragma unroll
  for (int u = 0; u < UPAIR; ++u) {
    float s = bias2;
    #pragma unroll
    for (int g = 0; g < NCHUNK; ++g) s += PART[(size_t)g * (NB*UPAIR) + (size_t)b * UPAIR + u];
    ord[u] = s;
  }
  float sc[NPAIR];
  #pragma unroll
  for (int p = 0; p < NPAIR; ++p) sc[p] = SC[(size_t)b * NPAIR + p];

  float res = 0.0f;
  #pragma unroll
  for (int i = 0; i < TEAM; ++i) {
    float m = sc[4*i];
    #pragma unroll
    for (int jj = 1; jj < 4; ++jj) m = fmaxf(m, sc[4*i + jj]);
    float e[4], d = 0.0f;
    #pragma unroll
    for (int jj = 0; jj < 4; ++jj) { e[jj] = __expf(sc[4*i + jj] - m); d += e[jj]; }
    const float inv = 1.0f / d;
    #pragma unroll
    for (int jj = 0; jj < 4; ++jj) {
      const int i2 = jj + (jj >= i ? 1 : 0);
      const int a  = i < i2 ? i : i2;
      const int bb = i < i2 ? i2 : i;
      const int u  = (a * (9 - a)) / 2 + (bb - a - 1);
      res += ord[u] * e[jj] * inv;
    }
  }
  out[b] = res;
}

// ---------------------------------------------------------------------------
extern "C" void kernel_launch(void* const* d_in, const int* in_sizes, int n_in,
                              void* d_out, int out_size, void* d_ws, size_t ws_size,
                              hipStream_t stream)
{
  (void)in_sizes; (void)n_in; (void)out_size; (void)ws_size;
  const int*   tids = (const int*)  d_in[0];
  const float* emb  = (const float*)d_in[1];
  const float* fw1  = (const float*)d_in[2];
  const float* fb1  = (const float*)d_in[3];
  const float* fw2  = (const float*)d_in[4];
  const float* fb2  = (const float*)d_in[5];
  const float* attw = (const float*)d_in[6];
  const float* attb = (const float*)d_in[7];
  const float* mw1  = (const float*)d_in[8];
  const float* mb1  = (const float*)d_in[9];
  const float* mw2  = (const float*)d_in[10];
  const float* mb2  = (const float*)d_in[11];
  float* out = (float*)d_out;

  float* H     = (float*)d_ws;                        // 81920*256 f32 = 84 MB
  float* SC    = H + (size_t)NPLAY * PD;              // NB*20 f32
  float* PART  = SC + (size_t)NB * NPAIR;             // NCHUNK*NB*10 f32
  short* w1f_m = (short*)(PART + (size_t)NCHUNK * NB * UPAIR); // mlp_w1 packed
  short* w1f_f = w1f_m + 262144;                      // fm_w1 packed
  short* w2f_f = w1f_f + 262144;                      // fm_w2 packed
  short* attf  = w2f_f + 262144;                      // att_w packed

  k_pack<<<512, 256, 0, stream>>>(mw1, w1f_m, 8, 131072);   // 512x256
  k_pack<<<512, 256, 0, stream>>>(fw1, w1f_f, 8, 131072);   // 512x256
  k_pack<<<512, 256, 0, stream>>>(fw2, w2f_f, 16, 131072);  // 256x512
  k_pack<<<256, 256, 0, stream>>>(attw, attf, 8, 65536);    // 256x256
  k_fm4<<<NPLAY/32, 256, 0, stream>>>(tids, emb, w1f_f, fb1, w2f_f, fb2, H);
  k_score<<<NB/8, 256, 0, stream>>>(H, attf, attb, SC);
  k_mlp<<<dim3(NB/8, NCHUNK), 256, 0, stream>>>(H, w1f_m, mb1, mw2, PART);
  k_final<<<NB/256, 256, 0, stream>>>(SC, PART, mb2, out);
}

// Round 8
// 665.216 us; speedup vs baseline: 11.8577x; 1.1117x over previous
//
#include <hip/hip_runtime.h>

#define NB     16384
#define TEAM   5
#define NPAIR  20
#define UPAIR  10             // unordered pairs: prod/order2 are symmetric in (i,j)
#define PD     256
#define HD     256
#define H1D    512
#define NPLAY  (NB*TEAM)      // 81920
#define NCHUNK 4              // k_mlp column chunks (y-grid)

typedef __attribute__((ext_vector_type(4))) float f32x4;
typedef __attribute__((ext_vector_type(8))) short s16x8;

__device__ __forceinline__ float silu_f(float x){ return x / (1.0f + __expf(-x)); }

__device__ __forceinline__ unsigned short bf16_rne(float x){
  unsigned u = __float_as_uint(x);
  unsigned r = u + 0x7fffu + ((u >> 16) & 1u);
  return (unsigned short)(r >> 16);
}
__device__ __forceinline__ float bf16_to_f(unsigned short s){
  return __uint_as_float(((unsigned)s) << 16);
}

// ---------------------------------------------------------------------------
// Generic prep: pack an N x K fp32 row-major matrix into MFMA B-fragment
// order, split bf16 hi/lo:  wf[h][nt][kt][lane][slot8],
// element = w[(nt*16 + (lane&15))*K + kt*32 + (lane>>4)*8 + slot].
// ---------------------------------------------------------------------------
__global__ void k_pack(const float* __restrict__ w, short* __restrict__ wf,
                       int KT, int total)
{
  const int tid = blockIdx.x * 256 + threadIdx.x;
  if (tid >= total) return;
  const int slot = tid & 7;
  const int lane = (tid >> 3) & 63;
  const int grp  = tid >> 9;
  const int kt   = grp % KT;
  const int nt   = grp / KT;
  const int K    = KT * 32;
  const int n = nt * 16 + (lane & 15);
  const int k = kt * 32 + ((lane >> 4) << 3) + slot;
  const float v = w[(size_t)n * K + k];
  const unsigned short hi = bf16_rne(v);
  const float lo = v - bf16_to_f(hi);
  wf[tid]         = (short)hi;
  wf[total + tid] = (short)bf16_rne(lo);
}

// ---------------------------------------------------------------------------
// Kernel A split (round-8): k_fm's 18% MfmaUtil plateau traced to thin
// MFMA/B-load ratio (3) + 1 MB B-stream per block. k_mlp's proven shape
// (5 M-tiles -> 60 MFMA per 8 B-loads, small B slice, ~21 KB LDS) applied
// to both FM layers, split via a global fp32 h1 buffer (168 MB, ws-gated).
// ---------------------------------------------------------------------------
// k_l1: h1[p][n] = silu(emb[tids[p]] @ w1^T + b1), N=512 sliced by cy in 2.
// Block: 80 players (5 mt) x 256 cols. A-frags per K64 chunk from emb.
__global__ __launch_bounds__(256) void k_l1(
    const int* __restrict__ tids, const float* __restrict__ emb,
    const short* __restrict__ w1f, const float* __restrict__ b1,
    float* __restrict__ Hh1)
{
  __shared__ short Af[2*5*2*512];   // [hilo][mt5][ks2][lane*8] : 20 KB
  __shared__ float Bb[256];
  __shared__ int   Tid[80];

  const int t = threadIdx.x, lane = t & 63, w = t >> 6;
  const int bx = blockIdx.x, cy = blockIdx.y;
  const int p0 = bx * 80;

  if (t < 80) Tid[t] = tids[p0 + t];
  Bb[t] = b1[cy * 256 + t];

  f32x4 acc[5][4];
  #pragma unroll
  for (int mt = 0; mt < 5; ++mt)
    #pragma unroll
    for (int j = 0; j < 4; ++j) acc[mt][j] = (f32x4){0.f,0.f,0.f,0.f};

  const s16x8* Bh = reinterpret_cast<const s16x8*>(w1f);   // hi; lo at +16384 units

  for (int kt = 0; kt < 8; ++kt) {
    const int kc = kt >> 1, ks = kt & 1;
    if (ks == 0) {
      __syncthreads();                  // prev chunk reads done / Tid ready
      const int kt0 = kc * 64;
      #pragma unroll
      for (int f = 0; f < 5; ++f) {
        const int idx4  = t + f * 256;            // 0..1279
        const int sg    = (idx4 & 1) * 4;
        const int lane_ = (idx4 >> 1) & 63;
        const int ks_   = (idx4 >> 7) & 1;
        const int mt_   = idx4 >> 8;              // 0..4
        const int p     = mt_ * 16 + (lane_ & 15);
        const int k     = kt0 + ks_ * 32 + ((lane_ >> 4) << 3) + sg;
        const int row   = Tid[p];
        const float4 a4 = *reinterpret_cast<const float4*>(emb + (size_t)row * PD + k);
        float pv[4] = {a4.x, a4.y, a4.z, a4.w};
        short hi[4], lo[4];
        #pragma unroll
        for (int e = 0; e < 4; ++e) {
          const unsigned short h = bf16_rne(pv[e]);
          hi[e] = (short)h;
          lo[e] = (short)bf16_rne(pv[e] - bf16_to_f(h));
        }
        const int aoff = (mt_ * 2 + ks_) * 512 + lane_ * 8 + sg;
        *reinterpret_cast<short4*>(&Af[aoff])        = make_short4(hi[0],hi[1],hi[2],hi[3]);
        *reinterpret_cast<short4*>(&Af[5120 + aoff]) = make_short4(lo[0],lo[1],lo[2],lo[3]);
      }
      __syncthreads();
    }

    s16x8 ah[5], al[5];
    #pragma unroll
    for (int mt = 0; mt < 5; ++mt) {
      ah[mt] = *reinterpret_cast<const s16x8*>(&Af[(mt*2 + ks)*512 + lane*8]);
      al[mt] = *reinterpret_cast<const s16x8*>(&Af[5120 + (mt*2 + ks)*512 + lane*8]);
    }
    #pragma unroll
    for (int j = 0; j < 4; ++j) {
      const int nt = cy * 16 + w * 4 + j;
      const s16x8 bh = Bh[(nt*8 + kt)*64 + lane];
      const s16x8 bl = Bh[16384 + (nt*8 + kt)*64 + lane];
      #pragma unroll
      for (int mt = 0; mt < 5; ++mt) {
        acc[mt][j] = __builtin_amdgcn_mfma_f32_16x16x32_bf16(ah[mt], bh, acc[mt][j], 0,0,0);
        acc[mt][j] = __builtin_amdgcn_mfma_f32_16x16x32_bf16(al[mt], bh, acc[mt][j], 0,0,0);
        acc[mt][j] = __builtin_amdgcn_mfma_f32_16x16x32_bf16(ah[mt], bl, acc[mt][j], 0,0,0);
      }
    }
  }

  // epilogue: bias + silu -> Hh1 fp32 C-layout (coalesced 64B segments)
  #pragma unroll
  for (int mt = 0; mt < 5; ++mt)
    #pragma unroll
    for (int j = 0; j < 4; ++j) {
      const int nl = w * 64 + j * 16 + (lane & 15);
      const int n  = cy * 256 + nl;
      #pragma unroll
      for (int r = 0; r < 4; ++r) {
        const int p = p0 + mt*16 + ((lane >> 4) << 2) + r;
        Hh1[(size_t)p * H1D + n] = silu_f(acc[mt][j][r] + Bb[nl]);
      }
    }
}

// k_l2: h[p][n] = h1[p] @ w2^T + b2, K=512, N=256.
// Block: 80 players (5 mt). A-frags per K64 chunk from fp32 Hh1.
__global__ __launch_bounds__(256) void k_l2(
    const float* __restrict__ Hh1, const short* __restrict__ w2f,
    const float* __restrict__ b2, float* __restrict__ Hout)
{
  __shared__ short Af[2*5*2*512];   // 20 KB
  __shared__ float Bb[256];

  const int t = threadIdx.x, lane = t & 63, w = t >> 6;
  const int bx = blockIdx.x;
  const int p0 = bx * 80;

  Bb[t] = b2[t];

  f32x4 acc[5][4];
  #pragma unroll
  for (int mt = 0; mt < 5; ++mt)
    #pragma unroll
    for (int j = 0; j < 4; ++j) acc[mt][j] = (f32x4){0.f,0.f,0.f,0.f};

  const s16x8* B2 = reinterpret_cast<const s16x8*>(w2f);   // hi; lo at +16384 units

  for (int kt = 0; kt < 16; ++kt) {
    const int kc = kt >> 1, ks = kt & 1;
    if (ks == 0) {
      __syncthreads();
      const int kt0 = kc * 64;
      #pragma unroll
      for (int f = 0; f < 5; ++f) {
        const int idx4  = t + f * 256;            // 0..1279
        const int sg    = (idx4 & 1) * 4;
        const int lane_ = (idx4 >> 1) & 63;
        const int ks_   = (idx4 >> 7) & 1;
        const int mt_   = idx4 >> 8;              // 0..4
        const int p     = p0 + mt_ * 16 + (lane_ & 15);
        const int k     = kt0 + ks_ * 32 + ((lane_ >> 4) << 3) + sg;
        const float4 a4 = *reinterpret_cast<const float4*>(Hh1 + (size_t)p * H1D + k);
        float pv[4] = {a4.x, a4.y, a4.z, a4.w};
        short hi[4], lo[4];
        #pragma unroll
        for (int e = 0; e < 4; ++e) {
          const unsigned short h = bf16_rne(pv[e]);
          hi[e] = (short)h;
          lo[e] = (short)bf16_rne(pv[e] - bf16_to_f(h));
        }
        const int aoff = (mt_ * 2 + ks_) * 512 + lane_ * 8 + sg;
        *reinterpret_cast<short4*>(&Af[aoff])        = make_short4(hi[0],hi[1],hi[2],hi[3]);
        *reinterpret_cast<short4*>(&Af[5120 + aoff]) = make_short4(lo[0],lo[1],lo[2],lo[3]);
      }
      __syncthreads();
    }

    s16x8 ah[5], al[5];
    #pragma unroll
    for (int mt = 0; mt < 5; ++mt) {
      ah[mt] = *reinterpret_cast<const s16x8*>(&Af[(mt*2 + ks)*512 + lane*8]);
      al[mt] = *reinterpret_cast<const s16x8*>(&Af[5120 + (mt*2 + ks)*512 + lane*8]);
    }
    #pragma unroll
    for (int j = 0; j < 4; ++j) {
      const int nt = w * 4 + j;
      const s16x8 bh = B2[(nt*16 + kt)*64 + lane];
      const s16x8 bl = B2[16384 + (nt*16 + kt)*64 + lane];
      #pragma unroll
      for (int mt = 0; mt < 5; ++mt) {
        acc[mt][j] = __builtin_amdgcn_mfma_f32_16x16x32_bf16(ah[mt], bh, acc[mt][j], 0,0,0);
        acc[mt][j] = __builtin_amdgcn_mfma_f32_16x16x32_bf16(al[mt], bh, acc[mt][j], 0,0,0);
        acc[mt][j] = __builtin_amdgcn_mfma_f32_16x16x32_bf16(ah[mt], bl, acc[mt][j], 0,0,0);
      }
    }
  }

  // epilogue: +b2, C-layout store
  #pragma unroll
  for (int mt = 0; mt < 5; ++mt)
    #pragma unroll
    for (int j = 0; j < 4; ++j) {
      const int n = w * 64 + j * 16 + (lane & 15);
      #pragma unroll
      for (int r = 0; r < 4; ++r) {
        const int p = p0 + mt*16 + ((lane >> 4) << 2) + r;
        Hout[(size_t)p * PD + n] = acc[mt][j][r] + Bb[n];
      }
    }
}

// ---------------------------------------------------------------------------
// Kernel A v4 (FALLBACK when ws too small for the split): unchanged round-7.
// ---------------------------------------------------------------------------
__global__ __launch_bounds__(256) void k_fm4(
    const int* __restrict__ tids, const float* __restrict__ emb,
    const short* __restrict__ w1f, const float* __restrict__ b1,
    const short* __restrict__ w2f, const float* __restrict__ b2,
    float* __restrict__ Hout)
{
  __shared__ char smem[65536 + 3072];
  short* Af  = reinterpret_cast<short*>(smem);
  short* H1f = reinterpret_cast<short*>(smem);
  float* Bb  = reinterpret_cast<float*>(smem + 65536);

  const int t = threadIdx.x, lane = t & 63, w = t >> 6;
  const int m0 = blockIdx.x * 32;

  Bb[t]       = b1[t];
  Bb[t + 256] = b1[t + 256];
  Bb[t + 512] = b2[t];

  #pragma unroll
  for (int f = 0; f < 8; ++f) {
    const int g     = t + f * 256;
    const int sg    = (g & 1) * 4;
    const int lane_ = (g >> 1) & 63;
    const int kt_   = (g >> 7) & 7;
    const int mt_   = g >> 10;
    const int p     = mt_ * 16 + (lane_ & 15);
    const int k     = kt_ * 32 + ((lane_ >> 4) << 3) + sg;
    const int row   = tids[m0 + p];
    const float4 a4 = *reinterpret_cast<const float4*>(emb + (size_t)row * PD + k);
    float pv[4] = {a4.x, a4.y, a4.z, a4.w};
    short hi[4], lo[4];
    #pragma unroll
    for (int e = 0; e < 4; ++e) {
      const unsigned short h = bf16_rne(pv[e]);
      hi[e] = (short)h;
      lo[e] = (short)bf16_rne(pv[e] - bf16_to_f(h));
    }
    const int off = ((mt_*8 + kt_)*64 + lane_)*8 + sg;
    *reinterpret_cast<short4*>(&Af[off])        = make_short4(hi[0],hi[1],hi[2],hi[3]);
    *reinterpret_cast<short4*>(&Af[8192 + off]) = make_short4(lo[0],lo[1],lo[2],lo[3]);
  }
  __syncthreads();

  const s16x8* B1 = reinterpret_cast<const s16x8*>(w1f);
  const s16x8* B2 = reinterpret_cast<const s16x8*>(w2f);

  f32x4 acc1[2][8];
  #pragma unroll
  for (int mt = 0; mt < 2; ++mt)
    #pragma unroll
    for (int j = 0; j < 8; ++j) acc1[mt][j] = (f32x4){0.f,0.f,0.f,0.f};

  #pragma unroll
  for (int kt = 0; kt < 8; ++kt) {
    s16x8 ah[2], al[2];
    #pragma unroll
    for (int mt = 0; mt < 2; ++mt) {
      ah[mt] = *reinterpret_cast<const s16x8*>(&Af[((mt*8 + kt)*64 + lane)*8]);
      al[mt] = *reinterpret_cast<const s16x8*>(&Af[8192 + ((mt*8 + kt)*64 + lane)*8]);
    }
    #pragma unroll
    for (int j = 0; j < 8; ++j) {
      const int nt = w * 8 + j;
      const s16x8 bh = B1[(nt*8 + kt)*64 + lane];
      const s16x8 bl = B1[16384 + (nt*8 + kt)*64 + lane];
      #pragma unroll
      for (int mt = 0; mt < 2; ++mt) {
        acc1[mt][j] = __builtin_amdgcn_mfma_f32_16x16x32_bf16(ah[mt], bh, acc1[mt][j], 0,0,0);
        acc1[mt][j] = __builtin_amdgcn_mfma_f32_16x16x32_bf16(al[mt], bh, acc1[mt][j], 0,0,0);
        acc1[mt][j] = __builtin_amdgcn_mfma_f32_16x16x32_bf16(ah[mt], bl, acc1[mt][j], 0,0,0);
      }
    }
  }
  __syncthreads();

  #pragma unroll
  for (int mt = 0; mt < 2; ++mt)
    #pragma unroll
    for (int j = 0; j < 8; ++j) {
      const int n     = w * 128 + j * 16 + (lane & 15);
      const int kt2   = n >> 5;
      const int lhalf = 16 * ((n >> 3) & 3);
      const int slot2 = n & 7;
      #pragma unroll
      for (int r = 0; r < 4; ++r) {
        const int prow = ((lane >> 4) << 2) + r;
        const float v = silu_f(acc1[mt][j][r] + Bb[n]);
        const unsigned short hi = bf16_rne(v);
        const int off = ((mt*16 + kt2)*64 + lhalf + prow)*8 + slot2;
        H1f[off]         = (short)hi;
        H1f[16384 + off] = (short)bf16_rne(v - bf16_to_f(hi));
      }
    }
  __syncthreads();

  f32x4 acc2[2][4];
  #pragma unroll
  for (int mt = 0; mt < 2; ++mt)
    #pragma unroll
    for (int j = 0; j < 4; ++j) acc2[mt][j] = (f32x4){0.f,0.f,0.f,0.f};

  #pragma unroll
  for (int kt = 0; kt < 16; ++kt) {
    s16x8 ah[2], al[2];
    #pragma unroll
    for (int mt = 0; mt < 2; ++mt) {
      ah[mt] = *reinterpret_cast<const s16x8*>(&H1f[((mt*16 + kt)*64 + lane)*8]);
      al[mt] = *reinterpret_cast<const s16x8*>(&H1f[16384 + ((mt*16 + kt)*64 + lane)*8]);
    }
    #pragma unroll
    for (int j = 0; j < 4; ++j) {
      const int nt = w * 4 + j;
      const s16x8 bh = B2[(nt*16 + kt)*64 + lane];
      const s16x8 bl = B2[16384 + (nt*16 + kt)*64 + lane];
      #pragma unroll
      for (int mt = 0; mt < 2; ++mt) {
        acc2[mt][j] = __builtin_amdgcn_mfma_f32_16x16x32_bf16(ah[mt], bh, acc2[mt][j], 0,0,0);
        acc2[mt][j] = __builtin_amdgcn_mfma_f32_16x16x32_bf16(al[mt], bh, acc2[mt][j], 0,0,0);
        acc2[mt][j] = __builtin_amdgcn_mfma_f32_16x16x32_bf16(ah[mt], bl, acc2[mt][j], 0,0,0);
      }
    }
  }

  #pragma unroll
  for (int mt = 0; mt < 2; ++mt)
    #pragma unroll
    for (int j = 0; j < 4; ++j) {
      const int n = w * 64 + j * 16 + (lane & 15);
      #pragma unroll
      for (int r = 0; r < 4; ++r) {
        const int p = m0 + mt*16 + ((lane >> 4) << 2) + r;
        Hout[(size_t)p * PD + n] = acc2[mt][j][r] + Bb[512 + n];
      }
    }
}

// ---------------------------------------------------------------------------
// Kernel B v3.1: att+score (unchanged from round 7).
// ---------------------------------------------------------------------------
__global__ __launch_bounds__(256) void k_score(
    const float* __restrict__ Hin, const short* __restrict__ attf,
    const float* __restrict__ attb, float* __restrict__ SC)
{
  __shared__ char smem[49152 + 1024];
  short* Hf  = reinterpret_cast<short*>(smem);
  float* WAl = reinterpret_cast<float*>(smem);
  float* Ab  = reinterpret_cast<float*>(smem + 49152);

  const int t = threadIdx.x, lane = t & 63, w = t >> 6;
  const int b0 = blockIdx.x * 8;
  const float* src = Hin + (size_t)b0 * TEAM * PD;

  Ab[t] = attb[t];

  #pragma unroll
  for (int f = 0; f < 12; ++f) {
    const int g     = t + f * 256;
    const int sg    = (g & 1) * 4;
    const int lane_ = (g >> 1) & 63;
    const int kt_   = (g >> 7) & 7;
    const int mt_   = g >> 10;
    const int p     = mt_ * 16 + (lane_ & 15);
    const int k     = kt_ * 32 + ((lane_ >> 4) << 3) + sg;
    float4 a4 = make_float4(0.f, 0.f, 0.f, 0.f);
    if (p < 40) a4 = *reinterpret_cast<const float4*>(src + (size_t)p * PD + k);
    float pv[4] = {a4.x, a4.y, a4.z, a4.w};
    short hi[4], lo[4];
    #pragma unroll
    for (int e = 0; e < 4; ++e) {
      const unsigned short h = bf16_rne(pv[e]);
      hi[e] = (short)h;
      lo[e] = (short)bf16_rne(pv[e] - bf16_to_f(h));
    }
    const int off = ((mt_*8 + kt_)*64 + lane_)*8 + sg;
    *reinterpret_cast<short4*>(&Hf[off])         = make_short4(hi[0],hi[1],hi[2],hi[3]);
    *reinterpret_cast<short4*>(&Hf[12288 + off]) = make_short4(lo[0],lo[1],lo[2],lo[3]);
  }
  __syncthreads();

  f32x4 acc[3][4];
  #pragma unroll
  for (int mt = 0; mt < 3; ++mt)
    #pragma unroll
    for (int j = 0; j < 4; ++j) acc[mt][j] = (f32x4){0.f,0.f,0.f,0.f};

  const s16x8* Bh = reinterpret_cast<const s16x8*>(attf);
  #pragma unroll
  for (int kt = 0; kt < 8; ++kt) {
    s16x8 ah[3], al[3];
    #pragma unroll
    for (int mt = 0; mt < 3; ++mt) {
      ah[mt] = *reinterpret_cast<const s16x8*>(&Hf[((mt*8 + kt)*64 + lane)*8]);
      al[mt] = *reinterpret_cast<const s16x8*>(&Hf[12288 + ((mt*8 + kt)*64 + lane)*8]);
    }
    #pragma unroll
    for (int j = 0; j < 4; ++j) {
      const int nt = w * 4 + j;
      const s16x8 bh = Bh[(nt*8 + kt)*64 + lane];
      const s16x8 bl = Bh[8192 + (nt*8 + kt)*64 + lane];
      #pragma unroll
      for (int mt = 0; mt < 3; ++mt) {
        acc[mt][j] = __builtin_amdgcn_mfma_f32_16x16x32_bf16(ah[mt], bh, acc[mt][j], 0,0,0);
        acc[mt][j] = __builtin_amdgcn_mfma_f32_16x16x32_bf16(al[mt], bh, acc[mt][j], 0,0,0);
        acc[mt][j] = __builtin_amdgcn_mfma_f32_16x16x32_bf16(ah[mt], bl, acc[mt][j], 0,0,0);
      }
    }
  }
  __syncthreads();

  #pragma unroll
  for (int mt = 0; mt < 3; ++mt)
    #pragma unroll
    for (int j = 0; j < 4; ++j) {
      const int n = w * 64 + j * 16 + (lane & 15);
      #pragma unroll
      for (int r = 0; r < 4; ++r) {
        const int row = mt * 16 + ((lane >> 4) << 2) + r;
        if (row < 40) WAl[row * 260 + n] = acc[mt][j][r] + Ab[n];
      }
    }
  __syncthreads();

  #pragma unroll
  for (int qq = 0; qq < 2; ++qq) {
    const int q = w * 2 + qq;
    #pragma unroll
    for (int p = 0; p < NPAIR; ++p) {
      const int i1 = p >> 2, jj = p & 3;
      const int i2 = jj + (jj >= i1 ? 1 : 0);
      const float4 a4 = *reinterpret_cast<const float4*>(WAl + (q*TEAM + i1) * 260 + lane * 4);
      const float4 b4 = *reinterpret_cast<const float4*>(src + (size_t)(q*TEAM + i2) * PD + lane * 4);
      float v = a4.x*b4.x + a4.y*b4.y + a4.z*b4.z + a4.w*b4.w;
      #pragma unroll
      for (int off = 32; off > 0; off >>= 1) v += __shfl_xor(v, off);
      if (lane == 0) SC[(size_t)(b0 + q) * NPAIR + p] = v;
    }
  }
}

// ---------------------------------------------------------------------------
// Kernel C: pair MLP on MFMA with split-bf16 (unchanged from round 3).
// ---------------------------------------------------------------------------
__global__ __launch_bounds__(256) void k_mlp(
    const float* __restrict__ Hin, const short* __restrict__ w1f,
    const float* __restrict__ b1, const float* __restrict__ w2,
    float* __restrict__ PART)
{
  __shared__ float Hl[40*260];
  __shared__ short Af[2*5*2*512];
  __shared__ float Wb[128];
  __shared__ float Ww[128];

  const int t    = threadIdx.x;
  const int lane = t & 63;
  const int w    = t >> 6;
  const int blkx = blockIdx.x;
  const int cy   = blockIdx.y;
  const int b0   = blkx * 8;

  {
    const float* src = Hin + (size_t)b0 * TEAM * PD;
    #pragma unroll
    for (int rep = 0; rep < 10; ++rep) {
      const int flat = t + rep * 256;
      const int row = flat >> 6, c4 = (flat & 63) * 4;
      *reinterpret_cast<float4*>(Hl + row * 260 + c4) =
        *reinterpret_cast<const float4*>(src + (size_t)row * PD + c4);
    }
    if (t < 128) { Wb[t] = b1[cy * 128 + t]; Ww[t] = w2[cy * 128 + t]; }
  }

  f32x4 acc[5][2];
  #pragma unroll
  for (int mt = 0; mt < 5; ++mt)
    #pragma unroll
    for (int j = 0; j < 2; ++j) acc[mt][j] = (f32x4){0.f,0.f,0.f,0.f};

  const s16x8* Bh = reinterpret_cast<const s16x8*>(w1f);
  const s16x8* Bl = reinterpret_cast<const s16x8*>(w1f + 131072);
  const int nt0 = cy * 8 + w * 2;

  for (int kt = 0; kt < 8; ++kt) {
    const int kc = kt >> 1, ks = kt & 1;
    if (ks == 0) {
      __syncthreads();
      const int kt0 = kc * 64;
      #pragma unroll
      for (int f = 0; f < 5; ++f) {
        const int idx4  = t + f * 256;
        const int sg    = (idx4 & 1) * 4;
        const int lane_ = (idx4 >> 1) & 63;
        const int ks_   = (idx4 >> 7) & 1;
        const int mt_   = idx4 >> 8;
        const int m  = lane_ & 15;
        const int r  = mt_ * 16 + m;
        const int q  = r / UPAIR;
        const int p  = r - q * UPAIR;
        const int i1 = (p >= 4) + (p >= 7) + (p >= 9);
        const int i2 = p - (i1 * (9 - i1)) / 2 + i1 + 1;
        const int kk = kt0 + ks_ * 32 + ((lane_ >> 4) << 3) + sg;
        const float4 a4 = *reinterpret_cast<const float4*>(Hl + (q*TEAM + i1)*260 + kk);
        const float4 b4 = *reinterpret_cast<const float4*>(Hl + (q*TEAM + i2)*260 + kk);
        float pv[4] = {a4.x*b4.x, a4.y*b4.y, a4.z*b4.z, a4.w*b4.w};
        short hi[4], lo[4];
        #pragma unroll
        for (int e = 0; e < 4; ++e) {
          const unsigned short h = bf16_rne(pv[e]);
          hi[e] = (short)h;
          lo[e] = (short)bf16_rne(pv[e] - bf16_to_f(h));
        }
        const int aoff = (mt_ * 2 + ks_) * 512 + lane_ * 8 + sg;
        *reinterpret_cast<short4*>(&Af[aoff])        = make_short4(hi[0],hi[1],hi[2],hi[3]);
        *reinterpret_cast<short4*>(&Af[5120 + aoff]) = make_short4(lo[0],lo[1],lo[2],lo[3]);
      }
      __syncthreads();
    }

    s16x8 ah[5], al[5];
    #pragma unroll
    for (int mt = 0; mt < 5; ++mt) {
      ah[mt] = *reinterpret_cast<const s16x8*>(&Af[(mt*2 + ks)*512 + lane*8]);
      al[mt] = *reinterpret_cast<const s16x8*>(&Af[5120 + (mt*2 + ks)*512 + lane*8]);
    }
    s16x8 bh[2], bl[2];
    #pragma unroll
    for (int j = 0; j < 2; ++j) {
      bh[j] = Bh[((nt0 + j)*8 + kt)*64 + lane];
      bl[j] = Bl[((nt0 + j)*8 + kt)*64 + lane];
    }
    #pragma unroll
    for (int mt = 0; mt < 5; ++mt)
      #pragma unroll
      for (int j = 0; j < 2; ++j) {
        acc[mt][j] = __builtin_amdgcn_mfma_f32_16x16x32_bf16(ah[mt], bh[j], acc[mt][j], 0,0,0);
        acc[mt][j] = __builtin_amdgcn_mfma_f32_16x16x32_bf16(ah[mt], bl[j], acc[mt][j], 0,0,0);
        acc[mt][j] = __builtin_amdgcn_mfma_f32_16x16x32_bf16(al[mt], bh[j], acc[mt][j], 0,0,0);
      }
  }

  __syncthreads();
  float* red = reinterpret_cast<float*>(Af);

  const int colbase = (w * 2) * 16 + (lane & 15);
  #pragma unroll
  for (int mt = 0; mt < 5; ++mt)
    #pragma unroll
    for (int r = 0; r < 4; ++r) {
      float s = 0.0f;
      #pragma unroll
      for (int j = 0; j < 2; ++j) {
        const int c = colbase + j * 16;
        s += silu_f(acc[mt][j][r] + Wb[c]) * Ww[c];
      }
      s += __shfl_xor(s, 1); s += __shfl_xor(s, 2);
      s += __shfl_xor(s, 4); s += __shfl_xor(s, 8);
      if ((lane & 15) == 0) {
        const int row = mt * 16 + ((lane >> 4) << 2) + r;
        red[row * 4 + w] = s;
      }
    }
  __syncthreads();
  if (t < 80) {
    const float s = red[t*4] + red[t*4+1] + red[t*4+2] + red[t*4+3];
    PART[(size_t)cy * (NB*UPAIR) + (size_t)blkx * 80 + t] = s;
  }
}

// ---------------------------------------------------------------------------
// Kernel D: one thread per batch (unchanged from round 3).
// ---------------------------------------------------------------------------
__global__ void k_final(const float* __restrict__ SC, const float* __restrict__ PART,
                        const float* __restrict__ mb2, float* __restrict__ out)
{
  const int b = blockIdx.x * 256 + threadIdx.x;
  if (b >= NB) return;
  const float bias2 = mb2[0];
  float ord[UPAIR];
  #pragma unroll
  for (int u = 0; u < UPAIR; ++u) {
    float s = bias2;
    #pragma unroll
    for (int g = 0; g < NCHUNK; ++g) s += PART[(size_t)g * (NB*UPAIR) + (size_t)b * UPAIR + u];
    ord[u] = s;
  }
  float sc[NPAIR];
  #pragma unroll
  for (int p = 0; p < NPAIR; ++p) sc[p] = SC[(size_t)b * NPAIR + p];

  float res = 0.0f;
  #pragma unroll
  for (int i = 0; i < TEAM; ++i) {
    float m = sc[4*i];
    #pragma unroll
    for (int jj = 1; jj < 4; ++jj) m = fmaxf(m, sc[4*i + jj]);
    float e[4], d = 0.0f;
    #pragma unroll
    for (int jj = 0; jj < 4; ++jj) { e[jj] = __expf(sc[4*i + jj] - m); d += e[jj]; }
    const float inv = 1.0f / d;
    #pragma unroll
    for (int jj = 0; jj < 4; ++jj) {
      const int i2 = jj + (jj >= i ? 1 : 0);
      const int a  = i < i2 ? i : i2;
      const int bb = i < i2 ? i2 : i;
      const int u  = (a * (9 - a)) / 2 + (bb - a - 1);
      res += ord[u] * e[jj] * inv;
    }
  }
  out[b] = res;
}

// ---------------------------------------------------------------------------
extern "C" void kernel_launch(void* const* d_in, const int* in_sizes, int n_in,
                              void* d_out, int out_size, void* d_ws, size_t ws_size,
                              hipStream_t stream)
{
  (void)in_sizes; (void)n_in; (void)out_size;
  const int*   tids = (const int*)  d_in[0];
  const float* emb  = (const float*)d_in[1];
  const float* fw1  = (const float*)d_in[2];
  const float* fb1  = (const float*)d_in[3];
  const float* fw2  = (const float*)d_in[4];
  const float* fb2  = (const float*)d_in[5];
  const float* attw = (const float*)d_in[6];
  const float* attb = (const float*)d_in[7];
  const float* mw1  = (const float*)d_in[8];
  const float* mb1  = (const float*)d_in[9];
  const float* mw2  = (const float*)d_in[10];
  const float* mb2  = (const float*)d_in[11];
  float* out = (float*)d_out;

  float* H     = (float*)d_ws;                        // 81920*256 f32 = 84 MB
  float* SC    = H + (size_t)NPLAY * PD;              // NB*20 f32
  float* PART  = SC + (size_t)NB * NPAIR;             // NCHUNK*NB*10 f32
  short* w1f_m = (short*)(PART + (size_t)NCHUNK * NB * UPAIR); // mlp_w1 packed
  short* w1f_f = w1f_m + 262144;                      // fm_w1 packed
  short* w2f_f = w1f_f + 262144;                      // fm_w2 packed
  short* attf  = w2f_f + 262144;                      // att_w packed
  float* Hh1   = (float*)(attf + 131072);             // 81920*512 f32 = 168 MB
  // bytes needed for the split path (Hh1 end):
  const size_t NEED = (size_t)((char*)(Hh1 + (size_t)NPLAY * H1D) - (char*)d_ws);

  k_pack<<<512, 256, 0, stream>>>(mw1, w1f_m, 8, 131072);   // 512x256
  k_pack<<<512, 256, 0, stream>>>(fw1, w1f_f, 8, 131072);   // 512x256
  k_pack<<<512, 256, 0, stream>>>(fw2, w2f_f, 16, 131072);  // 256x512
  k_pack<<<256, 256, 0, stream>>>(attw, attf, 8, 65536);    // 256x256

  if (ws_size >= NEED) {
    k_l1<<<dim3(NPLAY/80, 2), 256, 0, stream>>>(tids, emb, w1f_f, fb1, Hh1);
    k_l2<<<NPLAY/80, 256, 0, stream>>>(Hh1, w2f_f, fb2, H);
  } else {
    k_fm4<<<NPLAY/32, 256, 0, stream>>>(tids, emb, w1f_f, fb1, w2f_f, fb2, H);
  }
  k_score<<<NB/8, 256, 0, stream>>>(H, attf, attb, SC);
  k_mlp<<<dim3(NB/8, NCHUNK), 256, 0, stream>>>(H, w1f_m, mb1, mw2, PART);
  k_final<<<NB/256, 256, 0, stream>>>(SC, PART, mb2, out);
}